// Round 4
// baseline (361.152 us; speedup 1.0000x reference)
//
#include <hip/hip_runtime.h>
#include <hip/hip_bf16.h>

// Problem constants (fixed by reference)
#define DIM      64
#define NCODE    1024
#define NROWS    131072          // 32*64*64
#define BLK      256
#define SPLIT    2               // code-dimension split across blocks
#define SCODES   (NCODE / SPLIT) // codes handled per block (512)

// Output layout (concatenated in reference return order, all f32):
#define Q_OFF    0
#define DIFF_OFF 8388608
#define IND_OFF  8388609
#define NU_OFF   (8388609 + 131072)   // 8519681

// ---------------------------------------------------------------------------
// Prep: embedT[c][d] = embed[d][c];  hee[c] = 0.5 * sum_d embed[d][c]^2
__global__ __launch_bounds__(256) void vq_prep(const float* __restrict__ embed,
                                               float* __restrict__ embedT,
                                               float* __restrict__ hee) {
    int c = blockIdx.x * blockDim.x + threadIdx.x;   // 0..1023
    if (c >= NCODE) return;
    float s = 0.f;
#pragma unroll
    for (int d = 0; d < DIM; ++d) {
        float v = embed[d * NCODE + c];              // coalesced across lanes
        embedT[c * DIM + d] = v;
        s = fmaf(v, v, s);
    }
    hee[c] = 0.5f * s;
}

// ---------------------------------------------------------------------------
// Scoring, SGPR-e version: the e-row address is wave-uniform (readfirstlane
// pins it), so the backend emits s_load_dwordx4..x16 into SGPRs and the
// FMAs take e as the scalar operand (v_fmac_f32 v, s, v). Zero LDS use;
// the per-CU LDS unit (the round-3 bottleneck at ~10.7 cyc/ds_read_b128)
// is out of the loop entirely. x stays in VGPRs (64 floats -> ~90 VGPR,
// 4 waves/SIMD for SMEM latency hiding).
__global__ __launch_bounds__(256, 4) void vq_score(const float* __restrict__ input,
                                                   const float* __restrict__ embedT,
                                                   const float* __restrict__ hee,
                                                   float* __restrict__ pbest,
                                                   float* __restrict__ pidx) {
    const int tid   = threadIdx.x;
    const int r     = blockIdx.x * BLK + tid;            // one row per thread
    const int cbase = blockIdx.y * SCODES;               // code-group base

    // x row into registers (16 x float4 = 64 VGPRs).
    float4 xv[16];
    {
        const float4* px = (const float4*)(input + (size_t)r * DIM);
#pragma unroll
        for (int k = 0; k < 16; ++k) xv[k] = px[k];
    }

    float best = -3.402823466e+38f;
    int   bidx = 0;

#pragma unroll 1
    for (int c = 0; c < SCODES; ++c) {
        // Force the code index into an SGPR -> uniform e-row address.
        const int code = __builtin_amdgcn_readfirstlane(cbase + c);
        const float4* __restrict__ e4 = (const float4*)(embedT + (size_t)code * DIM);
        const float hh = hee[code];                      // uniform -> s_load

        // Same 4-chain grouping as the validated kernels (identical rounding).
        float a0 = -hh, a1 = 0.f, a2 = 0.f, a3 = 0.f;
#pragma unroll
        for (int k = 0; k < 16; ++k) {
            float4 e = e4[k];                            // uniform -> s_load_dwordx4+
            float4 p = xv[k];
            switch (k & 3) {
            case 0:
                a0 = fmaf(e.x, p.x, a0); a0 = fmaf(e.y, p.y, a0);
                a0 = fmaf(e.z, p.z, a0); a0 = fmaf(e.w, p.w, a0);
                break;
            case 1:
                a1 = fmaf(e.x, p.x, a1); a1 = fmaf(e.y, p.y, a1);
                a1 = fmaf(e.z, p.z, a1); a1 = fmaf(e.w, p.w, a1);
                break;
            case 2:
                a2 = fmaf(e.x, p.x, a2); a2 = fmaf(e.y, p.y, a2);
                a2 = fmaf(e.z, p.z, a2); a2 = fmaf(e.w, p.w, a2);
                break;
            default:
                a3 = fmaf(e.x, p.x, a3); a3 = fmaf(e.y, p.y, a3);
                a3 = fmaf(e.z, p.z, a3); a3 = fmaf(e.w, p.w, a3);
                break;
            }
        }
        float s = (a0 + a1) + (a2 + a3);
        // strict > with ascending c == first-index tie-break of argmin(dist)
        if (s > best) { best = s; bidx = code; }
    }

    size_t o = (size_t)blockIdx.y * NROWS;
    pbest[o + r] = best;
    pidx[o + r]  = (float)bidx;
}

// ---------------------------------------------------------------------------
// Combine: merge the SPLIT partials per row, gather code row, write outputs,
// accumulate deterministic MSE partial per block.
__global__ __launch_bounds__(256) void vq_combine(const float* __restrict__ input,
                                                  const float* __restrict__ embedT,
                                                  const float* __restrict__ pbest,
                                                  const float* __restrict__ pidx,
                                                  float* __restrict__ out_q,
                                                  float* __restrict__ out_ind,
                                                  float* __restrict__ partials) {
    __shared__ float wsum[4];
    const int tid = threadIdx.x;
    const int r   = blockIdx.x * BLK + tid;

    float p0 = pbest[r];
    float p1 = pbest[(size_t)NROWS + r];
    int   i0 = (int)pidx[r];
    int   i1 = (int)pidx[(size_t)NROWS + r];
    // strict > keeps lower index on exact tie (group-0 codes < group-1 codes)
    int bi = (p1 > p0) ? i1 : i0;
    out_ind[r] = (float)bi;

    float acc = 0.f;
    {
        const float4* x4 = (const float4*)(input + (size_t)r * DIM);
        const float4* q4 = (const float4*)(embedT + (size_t)bi * DIM);
        float4* o4 = (float4*)(out_q + (size_t)r * DIM);
#pragma unroll
        for (int k = 0; k < 16; ++k) {
            float4 q = q4[k];
            float4 x = x4[k];
            o4[k] = q;
            float dx = q.x - x.x; acc = fmaf(dx, dx, acc);
            dx = q.y - x.y;       acc = fmaf(dx, dx, acc);
            dx = q.z - x.z;       acc = fmaf(dx, dx, acc);
            dx = q.w - x.w;       acc = fmaf(dx, dx, acc);
        }
    }
#pragma unroll
    for (int off = 32; off > 0; off >>= 1) acc += __shfl_down(acc, off, 64);
    if ((tid & 63) == 0) wsum[tid >> 6] = acc;
    __syncthreads();
    if (tid == 0) partials[blockIdx.x] = (wsum[0] + wsum[1]) + (wsum[2] + wsum[3]);
}

// ---------------------------------------------------------------------------
// Finalize: deterministic reduction of 512 block partials -> mean; write -1.
__global__ __launch_bounds__(256) void vq_finalize(const float* __restrict__ partials,
                                                   float* __restrict__ out,
                                                   int out_size) {
    __shared__ float sm[256];
    int t = threadIdx.x;
    float v = partials[t] + partials[t + 256];
    sm[t] = v;
    __syncthreads();
    for (int s = 128; s > 0; s >>= 1) {
        if (t < s) sm[t] += sm[t + s];
        __syncthreads();
    }
    if (t == 0) out[DIFF_OFF] = sm[0] / 8388608.0f;
    if (t == 1 && out_size > NU_OFF) out[NU_OFF] = -1.0f;
}

// ---------------------------------------------------------------------------
extern "C" void kernel_launch(void* const* d_in, const int* in_sizes, int n_in,
                              void* d_out, int out_size, void* d_ws, size_t ws_size,
                              hipStream_t stream) {
    const float* input = (const float*)d_in[0];   // [32,64,64,64]
    const float* embed = (const float*)d_in[1];   // [64,1024]
    float* out = (float*)d_out;

    float* hee      = (float*)d_ws;               // 1024
    float* embedT   = hee + NCODE;                // 1024*64
    float* partials = embedT + NCODE * DIM;       // 512
    float* pbest    = partials + 512;             // SPLIT * NROWS
    float* pidx     = pbest + (size_t)SPLIT * NROWS;  // SPLIT * NROWS

    vq_prep<<<NCODE / 256, 256, 0, stream>>>(embed, embedT, hee);
    dim3 sgrid(NROWS / BLK, SPLIT);               // (512, 2), one row per thread
    vq_score<<<sgrid, BLK, 0, stream>>>(input, embedT, hee, pbest, pidx);
    vq_combine<<<NROWS / BLK, BLK, 0, stream>>>(input, embedT, pbest, pidx,
                                                out + Q_OFF, out + IND_OFF, partials);
    vq_finalize<<<1, 256, 0, stream>>>(partials, out, out_size);
}

// Round 5
// 173.326 us; speedup vs baseline: 2.0837x; 2.0837x over previous
//
#include <hip/hip_runtime.h>
#include <hip/hip_bf16.h>

// Problem constants (fixed by reference)
#define DIM      64
#define NCODE    1024
#define NROWS    131072          // 32*64*64
#define NTILES   64              // 1024 codes / 16 per MFMA tile
#define TAU      0.006f          // near-tie threshold (4x worst-case bf16x3 err)

typedef __attribute__((ext_vector_type(8))) short  short8;  // 8 bf16 (4 VGPRs)
typedef __attribute__((ext_vector_type(4))) float  f32x4;

// Output layout (concatenated in reference return order, all f32):
#define DIFF_OFF 8388608
#define IND_OFF  8388609
#define NU_OFF   (8388609 + 131072)

// ws layout (float offsets)
#define WS_HEE      0            // 1024
#define WS_EMBEDT   1024         // 65536
#define WS_PARTIALS 66560        // 512
#define WS_PIDX     67072        // 131072
#define WS_COUNTER  198144       // 1 (int)
#define WS_FLAGLIST 198145       // 131072 (int)
#define WS_BPK      329220       // 65536 floats = 256 KiB packed bf16 codebook

__device__ __forceinline__ unsigned short bf16rn(float f) {
    unsigned int u = __float_as_uint(f);
    return (unsigned short)((u + 0x7FFFu + ((u >> 16) & 1u)) >> 16);
}
__device__ __forceinline__ float bf16tof(unsigned short h) {
    return __uint_as_float(((unsigned int)h) << 16);
}

// ---------------------------------------------------------------------------
// Prep: embedT[c][d], hee[c] = 0.5*||e_c||^2, zero the flag counter.
__global__ __launch_bounds__(256) void vq_prep(const float* __restrict__ embed,
                                               float* __restrict__ embedT,
                                               float* __restrict__ hee,
                                               int* __restrict__ counter) {
    int c = blockIdx.x * blockDim.x + threadIdx.x;   // 0..1023
    if (c == 0) *counter = 0;
    if (c >= NCODE) return;
    float s = 0.f;
#pragma unroll
    for (int d = 0; d < DIM; ++d) {
        float v = embed[d * NCODE + c];
        embedT[c * DIM + d] = v;
        s = fmaf(v, v, s);
    }
    hee[c] = 0.5f * s;
}

// ---------------------------------------------------------------------------
// Pack codebook into B-fragment order, bf16 hi/lo.
// Tile ct (16 codes): 4 KiB block at ct*4096:
//   +0    : kstep0 hi   (lane l: 16B = 8 bf16, code ct*16+(l&15), k=(l>>4)*8..+7)
//   +1024 : kstep1 hi   (k = 32 + (l>>4)*8 ..)
//   +2048 : kstep0 lo
//   +3072 : kstep1 lo
__global__ __launch_bounds__(256) void vq_packB(const float* __restrict__ embed,
                                                unsigned char* __restrict__ bpk) {
    int t  = blockIdx.x * 256 + threadIdx.x;         // 0..8191
    int s  = t & 1;
    int l  = (t >> 1) & 63;
    int ct = t >> 7;
    int c  = ct * 16 + (l & 15);
    int kb = s * 32 + (l >> 4) * 8;

    unsigned int hw[4], lw[4];
#pragma unroll
    for (int w = 0; w < 4; ++w) {
        float v0 = embed[(kb + 2 * w)     * NCODE + c];
        float v1 = embed[(kb + 2 * w + 1) * NCODE + c];
        unsigned short h0 = bf16rn(v0), h1 = bf16rn(v1);
        unsigned short l0 = bf16rn(v0 - bf16tof(h0));
        unsigned short l1 = bf16rn(v1 - bf16tof(h1));
        hw[w] = (unsigned int)h0 | ((unsigned int)h1 << 16);
        lw[w] = (unsigned int)l0 | ((unsigned int)l1 << 16);
    }
    uint4* dst_h = (uint4*)(bpk + ct * 4096 + s * 1024 + l * 16);
    uint4* dst_l = (uint4*)(bpk + ct * 4096 + s * 1024 + l * 16 + 2048);
    *dst_h = make_uint4(hw[0], hw[1], hw[2], hw[3]);
    *dst_l = make_uint4(lw[0], lw[1], lw[2], lw[3]);
}

// ---------------------------------------------------------------------------
// MFMA scoring: each wave owns 64 rows (4 sets of 16) x all 1024 codes.
// score = bf16x3(x . e) - 0.5||e||^2 ; per-lane top-2 -> butterfly merge.
// Rows with (best - second) < TAU are flagged for exact f32 rescore.
__global__ __launch_bounds__(256) void vq_score_mfma(const float* __restrict__ input,
                                                     const unsigned char* __restrict__ bpk,
                                                     const float* __restrict__ hee,
                                                     float* __restrict__ pidx,
                                                     int* __restrict__ counter,
                                                     int* __restrict__ flaglist) {
    const int tid   = threadIdx.x;
    const int wid   = tid >> 6;
    const int lane  = tid & 63;
    const int g     = lane >> 4;          // k-group / D-row group
    const int lc    = lane & 15;          // A-row within set / D-col (code)
    const int rbase = (blockIdx.x * 4 + wid) * 64;

    // Build A fragments: 4 row-sets x 2 ksteps, hi+lo bf16.
    short8 ah[4][2], al[4][2];
#pragma unroll
    for (int m = 0; m < 4; ++m) {
#pragma unroll
        for (int s = 0; s < 2; ++s) {
            const float* xr = input + (size_t)(rbase + m * 16 + lc) * DIM + s * 32 + g * 8;
            float4 f0 = *(const float4*)(xr);
            float4 f1 = *(const float4*)(xr + 4);
            float xf[8] = {f0.x, f0.y, f0.z, f0.w, f1.x, f1.y, f1.z, f1.w};
            short8 h8, l8;
#pragma unroll
            for (int j = 0; j < 8; ++j) {
                unsigned short hb = bf16rn(xf[j]);
                h8[j] = (short)hb;
                l8[j] = (short)bf16rn(xf[j] - bf16tof(hb));
            }
            ah[m][s] = h8;
            al[m][s] = l8;
        }
    }

    float b1[16], b2[16];
    int   i1[16];
#pragma unroll
    for (int t = 0; t < 16; ++t) { b1[t] = -3.402823466e+38f; b2[t] = -3.402823466e+38f; i1[t] = 0; }

#pragma unroll 2
    for (int ct = 0; ct < NTILES; ++ct) {
        const unsigned char* tp = bpk + ct * 4096 + lane * 16;
        short8 bh0 = *(const short8*)(tp);
        short8 bh1 = *(const short8*)(tp + 1024);
        short8 bl0 = *(const short8*)(tp + 2048);
        short8 bl1 = *(const short8*)(tp + 3072);
        float  hh  = hee[ct * 16 + lc];
        int    code = ct * 16 + lc;

#pragma unroll
        for (int m = 0; m < 4; ++m) {
            f32x4 acc = {0.f, 0.f, 0.f, 0.f};
            acc = __builtin_amdgcn_mfma_f32_16x16x32_bf16(ah[m][0], bh0, acc, 0, 0, 0);
            acc = __builtin_amdgcn_mfma_f32_16x16x32_bf16(al[m][0], bh0, acc, 0, 0, 0);
            acc = __builtin_amdgcn_mfma_f32_16x16x32_bf16(ah[m][0], bl0, acc, 0, 0, 0);
            acc = __builtin_amdgcn_mfma_f32_16x16x32_bf16(ah[m][1], bh1, acc, 0, 0, 0);
            acc = __builtin_amdgcn_mfma_f32_16x16x32_bf16(al[m][1], bh1, acc, 0, 0, 0);
            acc = __builtin_amdgcn_mfma_f32_16x16x32_bf16(ah[m][1], bl1, acc, 0, 0, 0);
#pragma unroll
            for (int j = 0; j < 4; ++j) {
                float sc  = acc[j] - hh;          // D: row=(g*4+j), col=lc
                int   slt = m * 4 + j;
                float o1  = b1[slt];
                b2[slt] = fmaxf(b2[slt], fminf(sc, o1));   // top-2 insert
                bool p  = sc > o1;
                b1[slt] = p ? sc : o1;
                i1[slt] = p ? code : i1[slt];
            }
        }
    }

    // Cross-lane merge within each 16-lane group (same g => same rows).
#pragma unroll
    for (int m = 0; m < 4; ++m) {
#pragma unroll
        for (int j = 0; j < 4; ++j) {
            int   slt = m * 4 + j;
            float v1 = b1[slt], v2 = b2[slt];
            int   ii = i1[slt];
#pragma unroll
            for (int d = 1; d < 16; d <<= 1) {
                float o1 = __shfl_xor(v1, d, 64);
                int   oi = __shfl_xor(ii, d, 64);
                float o2 = __shfl_xor(v2, d, 64);
                bool  sw = (o1 > v1) || (o1 == v1 && oi < ii);
                float small1 = sw ? v1 : o1;
                v2 = fmaxf(fmaxf(v2, o2), small1);
                v1 = sw ? o1 : v1;
                ii = sw ? oi : ii;
            }
            if (lc == 0) {
                int r = rbase + m * 16 + g * 4 + j;
                pidx[r] = (float)ii;
                if (v1 - v2 < TAU) {
                    int p = atomicAdd(counter, 1);
                    flaglist[p] = r;
                }
            }
        }
    }
}

// ---------------------------------------------------------------------------
// Exact rescore of flagged rows: bit-identical 4-chain f32 formula of the
// validated rounds; one wave per row, 16 codes per lane.
__global__ __launch_bounds__(64) void vq_rescore(const float* __restrict__ input,
                                                 const float* __restrict__ embedT,
                                                 const float* __restrict__ hee,
                                                 const int* __restrict__ counter,
                                                 const int* __restrict__ flaglist,
                                                 float* __restrict__ pidx) {
    const int lane = threadIdx.x;
    const int cnt  = *counter;
    for (int i = blockIdx.x; i < cnt; i += gridDim.x) {
        const int r = flaglist[i];
        float4 xv[16];
        {
            const float4* px = (const float4*)(input + (size_t)r * DIM);
#pragma unroll
            for (int k = 0; k < 16; ++k) xv[k] = px[k];
        }
        float best = -3.402823466e+38f;
        int   bi = 0;
#pragma unroll 1
        for (int k = 0; k < 16; ++k) {
            int c = lane * 16 + k;
            const float4* e4 = (const float4*)(embedT + (size_t)c * DIM);
            float hh = hee[c];
            float a0 = -hh, a1 = 0.f, a2 = 0.f, a3 = 0.f;
#pragma unroll
            for (int q = 0; q < 4; ++q) {
                float4 e0 = e4[4 * q + 0], e1 = e4[4 * q + 1];
                float4 e2 = e4[4 * q + 2], e3 = e4[4 * q + 3];
                float4 x0 = xv[4 * q + 0], x1 = xv[4 * q + 1];
                float4 x2 = xv[4 * q + 2], x3 = xv[4 * q + 3];
                a0 = fmaf(e0.x, x0.x, a0); a0 = fmaf(e0.y, x0.y, a0);
                a0 = fmaf(e0.z, x0.z, a0); a0 = fmaf(e0.w, x0.w, a0);
                a1 = fmaf(e1.x, x1.x, a1); a1 = fmaf(e1.y, x1.y, a1);
                a1 = fmaf(e1.z, x1.z, a1); a1 = fmaf(e1.w, x1.w, a1);
                a2 = fmaf(e2.x, x2.x, a2); a2 = fmaf(e2.y, x2.y, a2);
                a2 = fmaf(e2.z, x2.z, a2); a2 = fmaf(e2.w, x2.w, a2);
                a3 = fmaf(e3.x, x3.x, a3); a3 = fmaf(e3.y, x3.y, a3);
                a3 = fmaf(e3.z, x3.z, a3); a3 = fmaf(e3.w, x3.w, a3);
            }
            float s = (a0 + a1) + (a2 + a3);
            if (s > best) { best = s; bi = c; }
        }
#pragma unroll
        for (int d = 1; d < 64; d <<= 1) {
            float ob = __shfl_xor(best, d, 64);
            int   oi = __shfl_xor(bi, d, 64);
            bool  sw = (ob > best) || (ob == best && oi < bi);
            best = sw ? ob : best;
            bi   = sw ? oi : bi;
        }
        if (lane == 0) pidx[r] = (float)bi;
    }
}

// ---------------------------------------------------------------------------
// Combine: gather code row, write quantize + ind, deterministic MSE partial.
__global__ __launch_bounds__(256) void vq_combine(const float* __restrict__ input,
                                                  const float* __restrict__ embedT,
                                                  const float* __restrict__ pidx,
                                                  float* __restrict__ out_q,
                                                  float* __restrict__ out_ind,
                                                  float* __restrict__ partials) {
    __shared__ float wsum[4];
    const int tid = threadIdx.x;
    const int r   = blockIdx.x * 256 + tid;

    int bi = (int)pidx[r];
    out_ind[r] = (float)bi;

    float acc = 0.f;
    {
        const float4* x4 = (const float4*)(input + (size_t)r * DIM);
        const float4* q4 = (const float4*)(embedT + (size_t)bi * DIM);
        float4* o4 = (float4*)(out_q + (size_t)r * DIM);
#pragma unroll
        for (int k = 0; k < 16; ++k) {
            float4 q = q4[k];
            float4 x = x4[k];
            o4[k] = q;
            float dx = q.x - x.x; acc = fmaf(dx, dx, acc);
            dx = q.y - x.y;       acc = fmaf(dx, dx, acc);
            dx = q.z - x.z;       acc = fmaf(dx, dx, acc);
            dx = q.w - x.w;       acc = fmaf(dx, dx, acc);
        }
    }
#pragma unroll
    for (int off = 32; off > 0; off >>= 1) acc += __shfl_down(acc, off, 64);
    if ((tid & 63) == 0) wsum[tid >> 6] = acc;
    __syncthreads();
    if (tid == 0) partials[blockIdx.x] = (wsum[0] + wsum[1]) + (wsum[2] + wsum[3]);
}

// ---------------------------------------------------------------------------
__global__ __launch_bounds__(256) void vq_finalize(const float* __restrict__ partials,
                                                   float* __restrict__ out,
                                                   int out_size) {
    __shared__ float sm[256];
    int t = threadIdx.x;
    float v = partials[t] + partials[t + 256];
    sm[t] = v;
    __syncthreads();
    for (int s = 128; s > 0; s >>= 1) {
        if (t < s) sm[t] += sm[t + s];
        __syncthreads();
    }
    if (t == 0) out[DIFF_OFF] = sm[0] / 8388608.0f;
    if (t == 1 && out_size > NU_OFF) out[NU_OFF] = -1.0f;
}

// ---------------------------------------------------------------------------
extern "C" void kernel_launch(void* const* d_in, const int* in_sizes, int n_in,
                              void* d_out, int out_size, void* d_ws, size_t ws_size,
                              hipStream_t stream) {
    const float* input = (const float*)d_in[0];   // [32,64,64,64]
    const float* embed = (const float*)d_in[1];   // [64,1024]
    float* out = (float*)d_out;
    float* ws  = (float*)d_ws;

    float* hee      = ws + WS_HEE;
    float* embedT   = ws + WS_EMBEDT;
    float* partials = ws + WS_PARTIALS;
    float* pidx     = ws + WS_PIDX;
    int*   counter  = (int*)(ws + WS_COUNTER);
    int*   flaglist = (int*)(ws + WS_FLAGLIST);
    unsigned char* bpk = (unsigned char*)(ws + WS_BPK);

    vq_prep<<<4, 256, 0, stream>>>(embed, embedT, hee, counter);
    vq_packB<<<32, 256, 0, stream>>>(embed, bpk);
    vq_score_mfma<<<512, 256, 0, stream>>>(input, bpk, hee, pidx, counter, flaglist);
    vq_rescore<<<64, 64, 0, stream>>>(input, embedT, hee, counter, flaglist, pidx);
    vq_combine<<<512, 256, 0, stream>>>(input, embedT, pidx,
                                        out, out + IND_OFF, partials);
    vq_finalize<<<1, 256, 0, stream>>>(partials, out, out_size);
}

// Round 6
// 120.076 us; speedup vs baseline: 3.0077x; 1.4435x over previous
//
#include <hip/hip_runtime.h>
#include <hip/hip_bf16.h>

// Problem constants (fixed by reference)
#define DIM      64
#define NCODE    1024
#define NROWS    131072          // 32*64*64
#define NTILES   64              // 1024 codes / 16 per MFMA tile
#define TAU      0.006f          // near-tie threshold (4x worst-case bf16x3 err)

typedef __attribute__((ext_vector_type(8))) short  short8;  // 8 bf16 (4 VGPRs)
typedef __attribute__((ext_vector_type(4))) float  f32x4;

// Output layout (concatenated in reference return order, all f32):
#define DIFF_OFF 8388608
#define IND_OFF  8388609
#define NU_OFF   (8388609 + 131072)

// ws layout (float offsets)
#define WS_HEE      0            // 1024
#define WS_EMBEDT   1024         // 65536
#define WS_PARTIALS 66560        // 512
#define WS_PIDX     67072        // 131072
#define WS_COUNTER  198144       // 1 (int)
#define WS_FLAGLIST 198145       // 131072 (int)
#define WS_BPK      329220       // 65536 floats = 256 KiB packed bf16 codebook

__device__ __forceinline__ unsigned short bf16rn(float f) {
    unsigned int u = __float_as_uint(f);
    return (unsigned short)((u + 0x7FFFu + ((u >> 16) & 1u)) >> 16);
}
__device__ __forceinline__ float bf16tof(unsigned short h) {
    return __uint_as_float(((unsigned int)h) << 16);
}

// ---------------------------------------------------------------------------
// Prep: embedT[c][d], hee[c] = 0.5*||e_c||^2, zero the flag counter.
__global__ __launch_bounds__(256) void vq_prep(const float* __restrict__ embed,
                                               float* __restrict__ embedT,
                                               float* __restrict__ hee,
                                               int* __restrict__ counter) {
    int c = blockIdx.x * blockDim.x + threadIdx.x;   // 0..1023
    if (c == 0) *counter = 0;
    if (c >= NCODE) return;
    float s = 0.f;
#pragma unroll
    for (int d = 0; d < DIM; ++d) {
        float v = embed[d * NCODE + c];
        embedT[c * DIM + d] = v;
        s = fmaf(v, v, s);
    }
    hee[c] = 0.5f * s;
}

// ---------------------------------------------------------------------------
// Pack codebook into B-fragment order, bf16 hi/lo.
// Tile ct (16 codes): 4 KiB block at ct*4096:
//   +0    : kstep0 hi   (lane l: 16B = 8 bf16, code ct*16+(l&15), k=(l>>4)*8..+7)
//   +1024 : kstep1 hi   (k = 32 + (l>>4)*8 ..)
//   +2048 : kstep0 lo
//   +3072 : kstep1 lo
__global__ __launch_bounds__(256) void vq_packB(const float* __restrict__ embed,
                                                unsigned char* __restrict__ bpk) {
    int t  = blockIdx.x * 256 + threadIdx.x;         // 0..8191
    int s  = t & 1;
    int l  = (t >> 1) & 63;
    int ct = t >> 7;
    int c  = ct * 16 + (l & 15);
    int kb = s * 32 + (l >> 4) * 8;

    unsigned int hw[4], lw[4];
#pragma unroll
    for (int w = 0; w < 4; ++w) {
        float v0 = embed[(kb + 2 * w)     * NCODE + c];
        float v1 = embed[(kb + 2 * w + 1) * NCODE + c];
        unsigned short h0 = bf16rn(v0), h1 = bf16rn(v1);
        unsigned short l0 = bf16rn(v0 - bf16tof(h0));
        unsigned short l1 = bf16rn(v1 - bf16tof(h1));
        hw[w] = (unsigned int)h0 | ((unsigned int)h1 << 16);
        lw[w] = (unsigned int)l0 | ((unsigned int)l1 << 16);
    }
    uint4* dst_h = (uint4*)(bpk + ct * 4096 + s * 1024 + l * 16);
    uint4* dst_l = (uint4*)(bpk + ct * 4096 + s * 1024 + l * 16 + 2048);
    *dst_h = make_uint4(hw[0], hw[1], hw[2], hw[3]);
    *dst_l = make_uint4(lw[0], lw[1], lw[2], lw[3]);
}

// ---------------------------------------------------------------------------
// MFMA scoring: each wave owns 64 rows (4 sets of 16) x all 1024 codes.
// score = bf16x3(x . e) - 0.5||e||^2 ; per-lane top-2 -> butterfly merge.
// Rows with (best - second) < TAU are flagged for exact f32 rescore.
__global__ __launch_bounds__(256) void vq_score_mfma(const float* __restrict__ input,
                                                     const unsigned char* __restrict__ bpk,
                                                     const float* __restrict__ hee,
                                                     float* __restrict__ pidx,
                                                     int* __restrict__ counter,
                                                     int* __restrict__ flaglist) {
    const int tid   = threadIdx.x;
    const int wid   = tid >> 6;
    const int lane  = tid & 63;
    const int g     = lane >> 4;          // k-group / D-row group
    const int lc    = lane & 15;          // A-row within set / D-col (code)
    const int rbase = (blockIdx.x * 4 + wid) * 64;

    // Build A fragments: 4 row-sets x 2 ksteps, hi+lo bf16.
    short8 ah[4][2], al[4][2];
#pragma unroll
    for (int m = 0; m < 4; ++m) {
#pragma unroll
        for (int s = 0; s < 2; ++s) {
            const float* xr = input + (size_t)(rbase + m * 16 + lc) * DIM + s * 32 + g * 8;
            float4 f0 = *(const float4*)(xr);
            float4 f1 = *(const float4*)(xr + 4);
            float xf[8] = {f0.x, f0.y, f0.z, f0.w, f1.x, f1.y, f1.z, f1.w};
            short8 h8, l8;
#pragma unroll
            for (int j = 0; j < 8; ++j) {
                unsigned short hb = bf16rn(xf[j]);
                h8[j] = (short)hb;
                l8[j] = (short)bf16rn(xf[j] - bf16tof(hb));
            }
            ah[m][s] = h8;
            al[m][s] = l8;
        }
    }

    float b1[16], b2[16];
    int   i1[16];
#pragma unroll
    for (int t = 0; t < 16; ++t) { b1[t] = -3.402823466e+38f; b2[t] = -3.402823466e+38f; i1[t] = 0; }

#pragma unroll 2
    for (int ct = 0; ct < NTILES; ++ct) {
        const unsigned char* tp = bpk + ct * 4096 + lane * 16;
        short8 bh0 = *(const short8*)(tp);
        short8 bh1 = *(const short8*)(tp + 1024);
        short8 bl0 = *(const short8*)(tp + 2048);
        short8 bl1 = *(const short8*)(tp + 3072);
        float  hh  = hee[ct * 16 + lc];
        int    code = ct * 16 + lc;

#pragma unroll
        for (int m = 0; m < 4; ++m) {
            f32x4 acc = {0.f, 0.f, 0.f, 0.f};
            acc = __builtin_amdgcn_mfma_f32_16x16x32_bf16(ah[m][0], bh0, acc, 0, 0, 0);
            acc = __builtin_amdgcn_mfma_f32_16x16x32_bf16(al[m][0], bh0, acc, 0, 0, 0);
            acc = __builtin_amdgcn_mfma_f32_16x16x32_bf16(ah[m][0], bl0, acc, 0, 0, 0);
            acc = __builtin_amdgcn_mfma_f32_16x16x32_bf16(ah[m][1], bh1, acc, 0, 0, 0);
            acc = __builtin_amdgcn_mfma_f32_16x16x32_bf16(al[m][1], bh1, acc, 0, 0, 0);
            acc = __builtin_amdgcn_mfma_f32_16x16x32_bf16(ah[m][1], bl1, acc, 0, 0, 0);
#pragma unroll
            for (int j = 0; j < 4; ++j) {
                float sc  = acc[j] - hh;          // D: row=(g*4+j), col=lc
                int   slt = m * 4 + j;
                float o1  = b1[slt];
                b2[slt] = fmaxf(b2[slt], fminf(sc, o1));   // top-2 insert
                bool p  = sc > o1;
                b1[slt] = p ? sc : o1;
                i1[slt] = p ? code : i1[slt];
            }
        }
    }

    // Cross-lane merge within each 16-lane group (same g => same rows).
#pragma unroll
    for (int m = 0; m < 4; ++m) {
#pragma unroll
        for (int j = 0; j < 4; ++j) {
            int   slt = m * 4 + j;
            float v1 = b1[slt], v2 = b2[slt];
            int   ii = i1[slt];
#pragma unroll
            for (int d = 1; d < 16; d <<= 1) {
                float o1 = __shfl_xor(v1, d, 64);
                int   oi = __shfl_xor(ii, d, 64);
                float o2 = __shfl_xor(v2, d, 64);
                bool  sw = (o1 > v1) || (o1 == v1 && oi < ii);
                float small1 = sw ? v1 : o1;
                v2 = fmaxf(fmaxf(v2, o2), small1);
                v1 = sw ? o1 : v1;
                ii = sw ? oi : ii;
            }
            if (lc == 0) {
                int r = rbase + m * 16 + g * 4 + j;
                pidx[r] = (float)ii;
                if (v1 - v2 < TAU) {
                    int p = atomicAdd(counter, 1);
                    flaglist[p] = r;
                }
            }
        }
    }
}

// ---------------------------------------------------------------------------
// Exact rescore of flagged rows: bit-identical 4-chain f32 formula of the
// validated rounds; ONE WAVE PER FLAGGED ROW (round-5 fix: was 64 waves for
// ~3500 rows -> 74 us latency-bound; now 2048 single-wave blocks grid-stride).
__global__ __launch_bounds__(64) void vq_rescore(const float* __restrict__ input,
                                                 const float* __restrict__ embedT,
                                                 const float* __restrict__ hee,
                                                 const int* __restrict__ counter,
                                                 const int* __restrict__ flaglist,
                                                 float* __restrict__ pidx) {
    const int lane = threadIdx.x;
    const int cnt  = *counter;
    for (int i = blockIdx.x; i < cnt; i += gridDim.x) {
        const int r = flaglist[i];
        float4 xv[16];
        {
            const float4* px = (const float4*)(input + (size_t)r * DIM);
#pragma unroll
            for (int k = 0; k < 16; ++k) xv[k] = px[k];
        }
        float best = -3.402823466e+38f;
        int   bi = 0;
#pragma unroll 1
        for (int k = 0; k < 16; ++k) {
            int c = lane * 16 + k;
            const float4* e4 = (const float4*)(embedT + (size_t)c * DIM);
            float hh = hee[c];
            float a0 = -hh, a1 = 0.f, a2 = 0.f, a3 = 0.f;
#pragma unroll
            for (int q = 0; q < 4; ++q) {
                float4 e0 = e4[4 * q + 0], e1 = e4[4 * q + 1];
                float4 e2 = e4[4 * q + 2], e3 = e4[4 * q + 3];
                float4 x0 = xv[4 * q + 0], x1 = xv[4 * q + 1];
                float4 x2 = xv[4 * q + 2], x3 = xv[4 * q + 3];
                a0 = fmaf(e0.x, x0.x, a0); a0 = fmaf(e0.y, x0.y, a0);
                a0 = fmaf(e0.z, x0.z, a0); a0 = fmaf(e0.w, x0.w, a0);
                a1 = fmaf(e1.x, x1.x, a1); a1 = fmaf(e1.y, x1.y, a1);
                a1 = fmaf(e1.z, x1.z, a1); a1 = fmaf(e1.w, x1.w, a1);
                a2 = fmaf(e2.x, x2.x, a2); a2 = fmaf(e2.y, x2.y, a2);
                a2 = fmaf(e2.z, x2.z, a2); a2 = fmaf(e2.w, x2.w, a2);
                a3 = fmaf(e3.x, x3.x, a3); a3 = fmaf(e3.y, x3.y, a3);
                a3 = fmaf(e3.z, x3.z, a3); a3 = fmaf(e3.w, x3.w, a3);
            }
            float s = (a0 + a1) + (a2 + a3);
            if (s > best) { best = s; bi = c; }
        }
#pragma unroll
        for (int d = 1; d < 64; d <<= 1) {
            float ob = __shfl_xor(best, d, 64);
            int   oi = __shfl_xor(bi, d, 64);
            bool  sw = (ob > best) || (ob == best && oi < bi);
            best = sw ? ob : best;
            bi   = sw ? oi : bi;
        }
        if (lane == 0) pidx[r] = (float)bi;
    }
}

// ---------------------------------------------------------------------------
// Combine: gather code row, write quantize + ind, deterministic MSE partial.
__global__ __launch_bounds__(256) void vq_combine(const float* __restrict__ input,
                                                  const float* __restrict__ embedT,
                                                  const float* __restrict__ pidx,
                                                  float* __restrict__ out_q,
                                                  float* __restrict__ out_ind,
                                                  float* __restrict__ partials) {
    __shared__ float wsum[4];
    const int tid = threadIdx.x;
    const int r   = blockIdx.x * 256 + tid;

    int bi = (int)pidx[r];
    out_ind[r] = (float)bi;

    float acc = 0.f;
    {
        const float4* x4 = (const float4*)(input + (size_t)r * DIM);
        const float4* q4 = (const float4*)(embedT + (size_t)bi * DIM);
        float4* o4 = (float4*)(out_q + (size_t)r * DIM);
#pragma unroll
        for (int k = 0; k < 16; ++k) {
            float4 q = q4[k];
            float4 x = x4[k];
            o4[k] = q;
            float dx = q.x - x.x; acc = fmaf(dx, dx, acc);
            dx = q.y - x.y;       acc = fmaf(dx, dx, acc);
            dx = q.z - x.z;       acc = fmaf(dx, dx, acc);
            dx = q.w - x.w;       acc = fmaf(dx, dx, acc);
        }
    }
#pragma unroll
    for (int off = 32; off > 0; off >>= 1) acc += __shfl_down(acc, off, 64);
    if ((tid & 63) == 0) wsum[tid >> 6] = acc;
    __syncthreads();
    if (tid == 0) partials[blockIdx.x] = (wsum[0] + wsum[1]) + (wsum[2] + wsum[3]);
}

// ---------------------------------------------------------------------------
__global__ __launch_bounds__(256) void vq_finalize(const float* __restrict__ partials,
                                                   float* __restrict__ out,
                                                   int out_size) {
    __shared__ float sm[256];
    int t = threadIdx.x;
    float v = partials[t] + partials[t + 256];
    sm[t] = v;
    __syncthreads();
    for (int s = 128; s > 0; s >>= 1) {
        if (t < s) sm[t] += sm[t + s];
        __syncthreads();
    }
    if (t == 0) out[DIFF_OFF] = sm[0] / 8388608.0f;
    if (t == 1 && out_size > NU_OFF) out[NU_OFF] = -1.0f;
}

// ---------------------------------------------------------------------------
extern "C" void kernel_launch(void* const* d_in, const int* in_sizes, int n_in,
                              void* d_out, int out_size, void* d_ws, size_t ws_size,
                              hipStream_t stream) {
    const float* input = (const float*)d_in[0];   // [32,64,64,64]
    const float* embed = (const float*)d_in[1];   // [64,1024]
    float* out = (float*)d_out;
    float* ws  = (float*)d_ws;

    float* hee      = ws + WS_HEE;
    float* embedT   = ws + WS_EMBEDT;
    float* partials = ws + WS_PARTIALS;
    float* pidx     = ws + WS_PIDX;
    int*   counter  = (int*)(ws + WS_COUNTER);
    int*   flaglist = (int*)(ws + WS_FLAGLIST);
    unsigned char* bpk = (unsigned char*)(ws + WS_BPK);

    vq_prep<<<4, 256, 0, stream>>>(embed, embedT, hee, counter);
    vq_packB<<<32, 256, 0, stream>>>(embed, bpk);
    vq_score_mfma<<<512, 256, 0, stream>>>(input, bpk, hee, pidx, counter, flaglist);
    vq_rescore<<<2048, 64, 0, stream>>>(input, embedT, hee, counter, flaglist, pidx);
    vq_combine<<<512, 256, 0, stream>>>(input, embedT, pidx,
                                        out, out + IND_OFF, partials);
    vq_finalize<<<1, 256, 0, stream>>>(partials, out, out_size);
}

// Round 7
// 119.337 us; speedup vs baseline: 3.0263x; 1.0062x over previous
//
#include <hip/hip_runtime.h>
#include <hip/hip_bf16.h>

// Problem constants (fixed by reference)
#define DIM      64
#define NCODE    1024
#define NROWS    131072          // 32*64*64
#define NTILES   64              // 1024 codes / 16 per MFMA tile
#define TAU      0.006f          // near-tie threshold (4x worst-case bf16x3 err)

typedef __attribute__((ext_vector_type(8))) short  short8;  // 8 bf16 (4 VGPRs)
typedef __attribute__((ext_vector_type(4))) float  f32x4;

// Output layout (concatenated in reference return order, all f32):
#define DIFF_OFF 8388608
#define IND_OFF  8388609
#define NU_OFF   (8388609 + 131072)

// ws layout (float offsets)
#define WS_HEE      0            // 1024
#define WS_EMBEDT   1024         // 65536
#define WS_PARTIALS 66560        // 512
#define WS_PIDX     67072        // 131072
#define WS_COUNTER  198144       // 1 (int)
#define WS_FLAGLIST 198145       // 131072 (int)
#define WS_BPK      329220       // 65536 floats = 256 KiB packed bf16 codebook

__device__ __forceinline__ unsigned short bf16rn(float f) {
    unsigned int u = __float_as_uint(f);
    return (unsigned short)((u + 0x7FFFu + ((u >> 16) & 1u)) >> 16);
}
__device__ __forceinline__ float bf16tof(unsigned short h) {
    return __uint_as_float(((unsigned int)h) << 16);
}

// ---------------------------------------------------------------------------
// Fused prep (blocks 0..3) + codebook pack (blocks 4..35).
// prep: embedT[c][d] = embed[d][c]; hee[c] = 0.5*||e_c||^2; zero counter.
// pack: tile ct (16 codes) -> 4 KiB at ct*4096:
//   +0 kstep0 hi | +1024 kstep1 hi | +2048 kstep0 lo | +3072 kstep1 lo
//   lane l: 16B = 8 bf16 of code ct*16+(l&15), k = base+(l>>4)*8 .. +7
__global__ __launch_bounds__(256) void vq_prep(const float* __restrict__ embed,
                                               float* __restrict__ embedT,
                                               float* __restrict__ hee,
                                               int* __restrict__ counter,
                                               unsigned char* __restrict__ bpk) {
    if (blockIdx.x < 4) {
        int c = blockIdx.x * 256 + threadIdx.x;      // 0..1023
        if (c == 0) *counter = 0;
        float s = 0.f;
#pragma unroll
        for (int d = 0; d < DIM; ++d) {
            float v = embed[d * NCODE + c];
            embedT[c * DIM + d] = v;
            s = fmaf(v, v, s);
        }
        hee[c] = 0.5f * s;
    } else {
        int t  = (blockIdx.x - 4) * 256 + threadIdx.x;   // 0..8191
        int s  = t & 1;
        int l  = (t >> 1) & 63;
        int ct = t >> 7;
        int c  = ct * 16 + (l & 15);
        int kb = s * 32 + (l >> 4) * 8;

        unsigned int hw[4], lw[4];
#pragma unroll
        for (int w = 0; w < 4; ++w) {
            float v0 = embed[(kb + 2 * w)     * NCODE + c];
            float v1 = embed[(kb + 2 * w + 1) * NCODE + c];
            unsigned short h0 = bf16rn(v0), h1 = bf16rn(v1);
            unsigned short l0 = bf16rn(v0 - bf16tof(h0));
            unsigned short l1 = bf16rn(v1 - bf16tof(h1));
            hw[w] = (unsigned int)h0 | ((unsigned int)h1 << 16);
            lw[w] = (unsigned int)l0 | ((unsigned int)l1 << 16);
        }
        uint4* dst_h = (uint4*)(bpk + ct * 4096 + s * 1024 + l * 16);
        uint4* dst_l = (uint4*)(bpk + ct * 4096 + s * 1024 + l * 16 + 2048);
        *dst_h = make_uint4(hw[0], hw[1], hw[2], hw[3]);
        *dst_l = make_uint4(lw[0], lw[1], lw[2], lw[3]);
    }
}

// ---------------------------------------------------------------------------
// MFMA scoring v2: each wave owns 32 rows (2 sets of 16) x all 1024 codes.
// Round-6 fixes for the latency-bound profile (19% occupancy, both pipes idle):
//   - 1024 blocks -> 4 waves/SIMD;  - register double-buffered bpk tile;
//   - -0.5||e||^2 folded into acc init (kills 16 VALU subs/tile).
__global__ __launch_bounds__(256, 4) void vq_score_mfma(const float* __restrict__ input,
                                                        const unsigned char* __restrict__ bpk,
                                                        const float* __restrict__ hee,
                                                        float* __restrict__ pidx,
                                                        int* __restrict__ counter,
                                                        int* __restrict__ flaglist) {
    const int tid   = threadIdx.x;
    const int wid   = tid >> 6;
    const int lane  = tid & 63;
    const int g     = lane >> 4;          // k-group / D-row group
    const int lc    = lane & 15;          // A-row within set / D-col (code)
    const int rbase = (blockIdx.x * 4 + wid) * 32;

    // Build A fragments: 2 row-sets x 2 ksteps, hi+lo bf16.
    short8 ah[2][2], al[2][2];
#pragma unroll
    for (int m = 0; m < 2; ++m) {
#pragma unroll
        for (int s = 0; s < 2; ++s) {
            const float* xr = input + (size_t)(rbase + m * 16 + lc) * DIM + s * 32 + g * 8;
            float4 f0 = *(const float4*)(xr);
            float4 f1 = *(const float4*)(xr + 4);
            float xf[8] = {f0.x, f0.y, f0.z, f0.w, f1.x, f1.y, f1.z, f1.w};
            short8 h8, l8;
#pragma unroll
            for (int j = 0; j < 8; ++j) {
                unsigned short hb = bf16rn(xf[j]);
                h8[j] = (short)hb;
                l8[j] = (short)bf16rn(xf[j] - bf16tof(hb));
            }
            ah[m][s] = h8;
            al[m][s] = l8;
        }
    }

    float b1[8], b2[8];
    int   i1[8];
#pragma unroll
    for (int t = 0; t < 8; ++t) { b1[t] = -3.402823466e+38f; b2[t] = -3.402823466e+38f; i1[t] = 0; }

    // Prefetch tile 0 into the current buffer.
    const unsigned char* tp0 = bpk + lane * 16;
    short8 c0 = *(const short8*)(tp0);
    short8 c1 = *(const short8*)(tp0 + 1024);
    short8 c2 = *(const short8*)(tp0 + 2048);
    short8 c3 = *(const short8*)(tp0 + 3072);
    float  chh = hee[lc];

#pragma unroll 2
    for (int ct = 0; ct < NTILES; ++ct) {
        // Prefetch next tile (clamped; redundant reload on the last iter).
        int nt = (ct + 1 < NTILES) ? ct + 1 : ct;
        const unsigned char* tp = bpk + nt * 4096 + lane * 16;
        short8 n0 = *(const short8*)(tp);
        short8 n1 = *(const short8*)(tp + 1024);
        short8 n2 = *(const short8*)(tp + 2048);
        short8 n3 = *(const short8*)(tp + 3072);
        float  nhh = hee[nt * 16 + lc];

        int code = ct * 16 + lc;
#pragma unroll
        for (int m = 0; m < 2; ++m) {
            f32x4 acc = {-chh, -chh, -chh, -chh};
            acc = __builtin_amdgcn_mfma_f32_16x16x32_bf16(ah[m][0], c0, acc, 0, 0, 0);
            acc = __builtin_amdgcn_mfma_f32_16x16x32_bf16(al[m][0], c0, acc, 0, 0, 0);
            acc = __builtin_amdgcn_mfma_f32_16x16x32_bf16(ah[m][0], c2, acc, 0, 0, 0);
            acc = __builtin_amdgcn_mfma_f32_16x16x32_bf16(ah[m][1], c1, acc, 0, 0, 0);
            acc = __builtin_amdgcn_mfma_f32_16x16x32_bf16(al[m][1], c1, acc, 0, 0, 0);
            acc = __builtin_amdgcn_mfma_f32_16x16x32_bf16(ah[m][1], c3, acc, 0, 0, 0);
#pragma unroll
            for (int j = 0; j < 4; ++j) {
                float sc  = acc[j];               // D: row=(g*4+j), col=lc
                int   slt = m * 4 + j;
                float o1  = b1[slt];
                b2[slt] = fmaxf(b2[slt], fminf(sc, o1));   // top-2 insert
                bool p  = sc > o1;
                b1[slt] = p ? sc : o1;
                i1[slt] = p ? code : i1[slt];
            }
        }
        c0 = n0; c1 = n1; c2 = n2; c3 = n3; chh = nhh;
    }

    // Cross-lane merge within each 16-lane group (same g => same rows).
#pragma unroll
    for (int m = 0; m < 2; ++m) {
#pragma unroll
        for (int j = 0; j < 4; ++j) {
            int   slt = m * 4 + j;
            float v1 = b1[slt], v2 = b2[slt];
            int   ii = i1[slt];
#pragma unroll
            for (int d = 1; d < 16; d <<= 1) {
                float o1 = __shfl_xor(v1, d, 64);
                int   oi = __shfl_xor(ii, d, 64);
                float o2 = __shfl_xor(v2, d, 64);
                bool  sw = (o1 > v1) || (o1 == v1 && oi < ii);
                float small1 = sw ? v1 : o1;
                v2 = fmaxf(fmaxf(v2, o2), small1);
                v1 = sw ? o1 : v1;
                ii = sw ? oi : ii;
            }
            if (lc == 0) {
                int r = rbase + m * 16 + g * 4 + j;
                pidx[r] = (float)ii;
                if (v1 - v2 < TAU) {
                    int p = atomicAdd(counter, 1);
                    flaglist[p] = r;
                }
            }
        }
    }
}

// ---------------------------------------------------------------------------
// Exact rescore of flagged rows: bit-identical 4-chain f32 formula of the
// validated rounds; one wave per flagged row, 2048 blocks grid-stride.
__global__ __launch_bounds__(64) void vq_rescore(const float* __restrict__ input,
                                                 const float* __restrict__ embedT,
                                                 const float* __restrict__ hee,
                                                 const int* __restrict__ counter,
                                                 const int* __restrict__ flaglist,
                                                 float* __restrict__ pidx) {
    const int lane = threadIdx.x;
    const int cnt  = *counter;
    for (int i = blockIdx.x; i < cnt; i += gridDim.x) {
        const int r = flaglist[i];
        float4 xv[16];
        {
            const float4* px = (const float4*)(input + (size_t)r * DIM);
#pragma unroll
            for (int k = 0; k < 16; ++k) xv[k] = px[k];
        }
        float best = -3.402823466e+38f;
        int   bi = 0;
#pragma unroll 1
        for (int k = 0; k < 16; ++k) {
            int c = lane * 16 + k;
            const float4* e4 = (const float4*)(embedT + (size_t)c * DIM);
            float hh = hee[c];
            float a0 = -hh, a1 = 0.f, a2 = 0.f, a3 = 0.f;
#pragma unroll
            for (int q = 0; q < 4; ++q) {
                float4 e0 = e4[4 * q + 0], e1 = e4[4 * q + 1];
                float4 e2 = e4[4 * q + 2], e3 = e4[4 * q + 3];
                float4 x0 = xv[4 * q + 0], x1 = xv[4 * q + 1];
                float4 x2 = xv[4 * q + 2], x3 = xv[4 * q + 3];
                a0 = fmaf(e0.x, x0.x, a0); a0 = fmaf(e0.y, x0.y, a0);
                a0 = fmaf(e0.z, x0.z, a0); a0 = fmaf(e0.w, x0.w, a0);
                a1 = fmaf(e1.x, x1.x, a1); a1 = fmaf(e1.y, x1.y, a1);
                a1 = fmaf(e1.z, x1.z, a1); a1 = fmaf(e1.w, x1.w, a1);
                a2 = fmaf(e2.x, x2.x, a2); a2 = fmaf(e2.y, x2.y, a2);
                a2 = fmaf(e2.z, x2.z, a2); a2 = fmaf(e2.w, x2.w, a2);
                a3 = fmaf(e3.x, x3.x, a3); a3 = fmaf(e3.y, x3.y, a3);
                a3 = fmaf(e3.z, x3.z, a3); a3 = fmaf(e3.w, x3.w, a3);
            }
            float s = (a0 + a1) + (a2 + a3);
            if (s > best) { best = s; bi = c; }
        }
#pragma unroll
        for (int d = 1; d < 64; d <<= 1) {
            float ob = __shfl_xor(best, d, 64);
            int   oi = __shfl_xor(bi, d, 64);
            bool  sw = (ob > best) || (ob == best && oi < bi);
            best = sw ? ob : best;
            bi   = sw ? oi : bi;
        }
        if (lane == 0) pidx[r] = (float)bi;
    }
}

// ---------------------------------------------------------------------------
// Combine: gather code row, write quantize + ind, deterministic MSE partial.
__global__ __launch_bounds__(256) void vq_combine(const float* __restrict__ input,
                                                  const float* __restrict__ embedT,
                                                  const float* __restrict__ pidx,
                                                  float* __restrict__ out_q,
                                                  float* __restrict__ out_ind,
                                                  float* __restrict__ partials) {
    __shared__ float wsum[4];
    const int tid = threadIdx.x;
    const int r   = blockIdx.x * 256 + tid;

    int bi = (int)pidx[r];
    out_ind[r] = (float)bi;

    float acc = 0.f;
    {
        const float4* x4 = (const float4*)(input + (size_t)r * DIM);
        const float4* q4 = (const float4*)(embedT + (size_t)bi * DIM);
        float4* o4 = (float4*)(out_q + (size_t)r * DIM);
#pragma unroll
        for (int k = 0; k < 16; ++k) {
            float4 q = q4[k];
            float4 x = x4[k];
            o4[k] = q;
            float dx = q.x - x.x; acc = fmaf(dx, dx, acc);
            dx = q.y - x.y;       acc = fmaf(dx, dx, acc);
            dx = q.z - x.z;       acc = fmaf(dx, dx, acc);
            dx = q.w - x.w;       acc = fmaf(dx, dx, acc);
        }
    }
#pragma unroll
    for (int off = 32; off > 0; off >>= 1) acc += __shfl_down(acc, off, 64);
    if ((tid & 63) == 0) wsum[tid >> 6] = acc;
    __syncthreads();
    if (tid == 0) partials[blockIdx.x] = (wsum[0] + wsum[1]) + (wsum[2] + wsum[3]);
}

// ---------------------------------------------------------------------------
__global__ __launch_bounds__(256) void vq_finalize(const float* __restrict__ partials,
                                                   float* __restrict__ out,
                                                   int out_size) {
    __shared__ float sm[256];
    int t = threadIdx.x;
    float v = partials[t] + partials[t + 256];
    sm[t] = v;
    __syncthreads();
    for (int s = 128; s > 0; s >>= 1) {
        if (t < s) sm[t] += sm[t + s];
        __syncthreads();
    }
    if (t == 0) out[DIFF_OFF] = sm[0] / 8388608.0f;
    if (t == 1 && out_size > NU_OFF) out[NU_OFF] = -1.0f;
}

// ---------------------------------------------------------------------------
extern "C" void kernel_launch(void* const* d_in, const int* in_sizes, int n_in,
                              void* d_out, int out_size, void* d_ws, size_t ws_size,
                              hipStream_t stream) {
    const float* input = (const float*)d_in[0];   // [32,64,64,64]
    const float* embed = (const float*)d_in[1];   // [64,1024]
    float* out = (float*)d_out;
    float* ws  = (float*)d_ws;

    float* hee      = ws + WS_HEE;
    float* embedT   = ws + WS_EMBEDT;
    float* partials = ws + WS_PARTIALS;
    float* pidx     = ws + WS_PIDX;
    int*   counter  = (int*)(ws + WS_COUNTER);
    int*   flaglist = (int*)(ws + WS_FLAGLIST);
    unsigned char* bpk = (unsigned char*)(ws + WS_BPK);

    vq_prep<<<36, 256, 0, stream>>>(embed, embedT, hee, counter, bpk);
    vq_score_mfma<<<1024, 256, 0, stream>>>(input, bpk, hee, pidx, counter, flaglist);
    vq_rescore<<<2048, 64, 0, stream>>>(input, embedT, hee, counter, flaglist, pidx);
    vq_combine<<<512, 256, 0, stream>>>(input, embedT, pidx,
                                        out, out + IND_OFF, partials);
    vq_finalize<<<1, 256, 0, stream>>>(partials, out, out_size);
}

// Round 8
// 115.653 us; speedup vs baseline: 3.1227x; 1.0318x over previous
//
#include <hip/hip_runtime.h>
#include <hip/hip_bf16.h>

// Problem constants (fixed by reference)
#define DIM      64
#define NCODE    1024
#define NROWS    131072          // 32*64*64
#define NTILES   64              // 1024 codes / 16 per MFMA tile
#define TAU      0.006f          // near-tie threshold (covers screen+mask error 4x)

typedef __attribute__((ext_vector_type(8))) short  short8;  // 8 bf16 (4 VGPRs)
typedef __attribute__((ext_vector_type(4))) float  f32x4;

// Output layout (concatenated in reference return order, all f32):
#define DIFF_OFF 8388608
#define IND_OFF  8388609
#define NU_OFF   (8388609 + 131072)

// ws layout (float offsets)
#define WS_HEE      0            // 1024
#define WS_EMBEDT   1024         // 65536
#define WS_PARTIALS 66560        // 512
#define WS_PIDX     67072        // 131072
#define WS_COUNTER  198144       // 1 (int)
#define WS_FLAGLIST 198145       // 131072 (int)
#define WS_BPK      329220       // 65536 floats = 256 KiB packed bf16 codebook

__device__ __forceinline__ unsigned short bf16rn(float f) {
    unsigned int u = __float_as_uint(f);
    return (unsigned short)((u + 0x7FFFu + ((u >> 16) & 1u)) >> 16);
}
__device__ __forceinline__ float bf16tof(unsigned short h) {
    return __uint_as_float(((unsigned int)h) << 16);
}
__device__ __forceinline__ unsigned umin_(unsigned a, unsigned b) { return a < b ? a : b; }
__device__ __forceinline__ unsigned umax_(unsigned a, unsigned b) { return a > b ? a : b; }

// ---------------------------------------------------------------------------
// Fused prep (blocks 0..3) + codebook pack (blocks 4..35).
// prep: embedT[c][d] = embed[d][c]; hee[c] = 0.5*||e_c||^2; zero counter.
// pack: tile ct (16 codes) -> 4 KiB at ct*4096:
//   +0 kstep0 hi | +1024 kstep1 hi | +2048 kstep0 lo | +3072 kstep1 lo
//   lane l: 16B = 8 bf16 of code ct*16+(l&15), k = base+(l>>4)*8 .. +7
__global__ __launch_bounds__(256) void vq_prep(const float* __restrict__ embed,
                                               float* __restrict__ embedT,
                                               float* __restrict__ hee,
                                               int* __restrict__ counter,
                                               unsigned char* __restrict__ bpk) {
    if (blockIdx.x < 4) {
        int c = blockIdx.x * 256 + threadIdx.x;      // 0..1023
        if (c == 0) *counter = 0;
        float s = 0.f;
#pragma unroll
        for (int d = 0; d < DIM; ++d) {
            float v = embed[d * NCODE + c];
            embedT[c * DIM + d] = v;
            s = fmaf(v, v, s);
        }
        hee[c] = 0.5f * s;
    } else {
        int t  = (blockIdx.x - 4) * 256 + threadIdx.x;   // 0..8191
        int s  = t & 1;
        int l  = (t >> 1) & 63;
        int ct = t >> 7;
        int c  = ct * 16 + (l & 15);
        int kb = s * 32 + (l >> 4) * 8;

        unsigned int hw[4], lw[4];
#pragma unroll
        for (int w = 0; w < 4; ++w) {
            float v0 = embed[(kb + 2 * w)     * NCODE + c];
            float v1 = embed[(kb + 2 * w + 1) * NCODE + c];
            unsigned short h0 = bf16rn(v0), h1 = bf16rn(v1);
            unsigned short l0 = bf16rn(v0 - bf16tof(h0));
            unsigned short l1 = bf16rn(v1 - bf16tof(h1));
            hw[w] = (unsigned int)h0 | ((unsigned int)h1 << 16);
            lw[w] = (unsigned int)l0 | ((unsigned int)l1 << 16);
        }
        uint4* dst_h = (uint4*)(bpk + ct * 4096 + s * 1024 + l * 16);
        uint4* dst_l = (uint4*)(bpk + ct * 4096 + s * 1024 + l * 16 + 2048);
        *dst_h = make_uint4(hw[0], hw[1], hw[2], hw[3]);
        *dst_l = make_uint4(lw[0], lw[1], lw[2], lw[3]);
    }
}

// ---------------------------------------------------------------------------
// MFMA scoring v3 (issue-bound fix): distance-form packed-u32 selection.
//   d = (0.5||x||^2 + 1) + 0.5||e||^2 - x.e  > 0  (A-frags hold -x)
//   pk = (d_bits & ~63) | tile_id  -> top-2 via u32 min/max (4 VALU/elem).
// Rigor: masked+screen error < TAU/2 -> any possible misorder is flagged and
// exactly rescored; first-index tie-break preserved via packed tile id.
__global__ __launch_bounds__(256, 4) void vq_score_mfma(const float* __restrict__ input,
                                                        const unsigned char* __restrict__ bpk,
                                                        const float* __restrict__ hee,
                                                        float* __restrict__ pidx,
                                                        int* __restrict__ counter,
                                                        int* __restrict__ flaglist) {
    const int tid   = threadIdx.x;
    const int wid   = tid >> 6;
    const int lane  = tid & 63;
    const int g     = lane >> 4;          // k-group / D-row group
    const int lc    = lane & 15;          // A-row within set / D-col (code)
    const int rbase = (blockIdx.x * 4 + wid) * 32;

    // Build A fragments (NEGATED x, hi+lo bf16) and per-slot hx = 0.5||x||^2+1.
    short8 ah[2][2], al[2][2];
    float  hx[2][4];
#pragma unroll
    for (int m = 0; m < 2; ++m) {
        float ssum = 0.f;
#pragma unroll
        for (int s = 0; s < 2; ++s) {
            const float* xr = input + (size_t)(rbase + m * 16 + lc) * DIM + s * 32 + g * 8;
            float4 f0 = *(const float4*)(xr);
            float4 f1 = *(const float4*)(xr + 4);
            float xf[8] = {f0.x, f0.y, f0.z, f0.w, f1.x, f1.y, f1.z, f1.w};
            short8 h8, l8;
#pragma unroll
            for (int j = 0; j < 8; ++j) {
                ssum = fmaf(xf[j], xf[j], ssum);
                float nx = -xf[j];
                unsigned short hb = bf16rn(nx);
                h8[j] = (short)hb;
                l8[j] = (short)bf16rn(nx - bf16tof(hb));
            }
            ah[m][s] = h8;
            al[m][s] = l8;
        }
        // row-sum across the 4 k-groups (lanes lc, lc+16, lc+32, lc+48)
        ssum += __shfl_xor(ssum, 16, 64);
        ssum += __shfl_xor(ssum, 32, 64);
        // slot (m,j) needs row rbase+m*16+g*4+j -> held by lane (g*4+j)
#pragma unroll
        for (int j = 0; j < 4; ++j)
            hx[m][j] = 0.5f * __shfl(ssum, g * 4 + j, 64) + 1.0f;
    }

    unsigned m1[8], m2[8];
#pragma unroll
    for (int t = 0; t < 8; ++t) { m1[t] = 0xFFFFFFFFu; m2[t] = 0xFFFFFFFFu; }

    // Prefetch tile 0.
    const unsigned char* tp0 = bpk + lane * 16;
    short8 c0 = *(const short8*)(tp0);
    short8 c1 = *(const short8*)(tp0 + 1024);
    short8 c2 = *(const short8*)(tp0 + 2048);
    short8 c3 = *(const short8*)(tp0 + 3072);
    float  chh = hee[lc];

    for (int ct = 0; ct < NTILES - 1; ++ct) {
        // Prefetch next tile.
        const unsigned char* tp = bpk + (ct + 1) * 4096 + lane * 16;
        short8 n0 = *(const short8*)(tp);
        short8 n1 = *(const short8*)(tp + 1024);
        short8 n2 = *(const short8*)(tp + 2048);
        short8 n3 = *(const short8*)(tp + 3072);
        float  nhh = hee[(ct + 1) * 16 + lc];

#pragma unroll
        for (int m = 0; m < 2; ++m) {
            f32x4 acc = {chh + hx[m][0], chh + hx[m][1], chh + hx[m][2], chh + hx[m][3]};
            acc = __builtin_amdgcn_mfma_f32_16x16x32_bf16(ah[m][0], c0, acc, 0, 0, 0);
            acc = __builtin_amdgcn_mfma_f32_16x16x32_bf16(al[m][0], c0, acc, 0, 0, 0);
            acc = __builtin_amdgcn_mfma_f32_16x16x32_bf16(ah[m][0], c2, acc, 0, 0, 0);
            acc = __builtin_amdgcn_mfma_f32_16x16x32_bf16(ah[m][1], c1, acc, 0, 0, 0);
            acc = __builtin_amdgcn_mfma_f32_16x16x32_bf16(al[m][1], c1, acc, 0, 0, 0);
            acc = __builtin_amdgcn_mfma_f32_16x16x32_bf16(ah[m][1], c3, acc, 0, 0, 0);
#pragma unroll
            for (int j = 0; j < 4; ++j) {
                unsigned bits = __float_as_uint(acc[j]);        // d > 0 -> u32-ordered
                unsigned pk   = (bits & 0xFFFFFFC0u) | (unsigned)ct;
                int s = m * 4 + j;
                m2[s] = umin_(m2[s], umax_(pk, m1[s]));
                m1[s] = umin_(m1[s], pk);
            }
        }
        c0 = n0; c1 = n1; c2 = n2; c3 = n3; chh = nhh;
    }
    // Last tile (no prefetch).
    {
        const int ct = NTILES - 1;
#pragma unroll
        for (int m = 0; m < 2; ++m) {
            f32x4 acc = {chh + hx[m][0], chh + hx[m][1], chh + hx[m][2], chh + hx[m][3]};
            acc = __builtin_amdgcn_mfma_f32_16x16x32_bf16(ah[m][0], c0, acc, 0, 0, 0);
            acc = __builtin_amdgcn_mfma_f32_16x16x32_bf16(al[m][0], c0, acc, 0, 0, 0);
            acc = __builtin_amdgcn_mfma_f32_16x16x32_bf16(ah[m][0], c2, acc, 0, 0, 0);
            acc = __builtin_amdgcn_mfma_f32_16x16x32_bf16(ah[m][1], c1, acc, 0, 0, 0);
            acc = __builtin_amdgcn_mfma_f32_16x16x32_bf16(al[m][1], c1, acc, 0, 0, 0);
            acc = __builtin_amdgcn_mfma_f32_16x16x32_bf16(ah[m][1], c3, acc, 0, 0, 0);
#pragma unroll
            for (int j = 0; j < 4; ++j) {
                unsigned bits = __float_as_uint(acc[j]);
                unsigned pk   = (bits & 0xFFFFFFC0u) | (unsigned)ct;
                int s = m * 4 + j;
                m2[s] = umin_(m2[s], umax_(pk, m1[s]));
                m1[s] = umin_(m1[s], pk);
            }
        }
    }

    // Cross-lane merge within each 16-lane group (same g => same rows).
#pragma unroll
    for (int m = 0; m < 2; ++m) {
#pragma unroll
        for (int j = 0; j < 4; ++j) {
            int s = m * 4 + j;
            unsigned v1 = m1[s], v2 = m2[s];
            int ii = (int)(((v1 & 63u) << 4) | (unsigned)lc);   // full code
#pragma unroll
            for (int d = 1; d < 16; d <<= 1) {
                unsigned o1 = __shfl_xor(v1, d, 64);
                int      oi = __shfl_xor(ii, d, 64);
                unsigned o2 = __shfl_xor(v2, d, 64);
                bool sw = (o1 < v1) || (o1 == v1 && oi < ii);
                unsigned losing = sw ? v1 : o1;                 // larger best
                v2 = umin_(umin_(v2, o2), losing);              // v_min3_u32
                v1 = sw ? o1 : v1;
                ii = sw ? oi : ii;
            }
            if (lc == 0) {
                int r = rbase + m * 16 + g * 4 + j;
                pidx[r] = (float)ii;
                float gap = __uint_as_float(v2 & 0xFFFFFFC0u)
                          - __uint_as_float(v1 & 0xFFFFFFC0u);
                if (gap < TAU) {
                    int p = atomicAdd(counter, 1);
                    flaglist[p] = r;
                }
            }
        }
    }
}

// ---------------------------------------------------------------------------
// Exact rescore of flagged rows: bit-identical 4-chain f32 formula of the
// validated rounds; one wave per flagged row, 2048 blocks grid-stride.
__global__ __launch_bounds__(64) void vq_rescore(const float* __restrict__ input,
                                                 const float* __restrict__ embedT,
                                                 const float* __restrict__ hee,
                                                 const int* __restrict__ counter,
                                                 const int* __restrict__ flaglist,
                                                 float* __restrict__ pidx) {
    const int lane = threadIdx.x;
    const int cnt  = *counter;
    for (int i = blockIdx.x; i < cnt; i += gridDim.x) {
        const int r = flaglist[i];
        float4 xv[16];
        {
            const float4* px = (const float4*)(input + (size_t)r * DIM);
#pragma unroll
            for (int k = 0; k < 16; ++k) xv[k] = px[k];
        }
        float best = -3.402823466e+38f;
        int   bi = 0;
#pragma unroll 1
        for (int k = 0; k < 16; ++k) {
            int c = lane * 16 + k;
            const float4* e4 = (const float4*)(embedT + (size_t)c * DIM);
            float hh = hee[c];
            float a0 = -hh, a1 = 0.f, a2 = 0.f, a3 = 0.f;
#pragma unroll
            for (int q = 0; q < 4; ++q) {
                float4 e0 = e4[4 * q + 0], e1 = e4[4 * q + 1];
                float4 e2 = e4[4 * q + 2], e3 = e4[4 * q + 3];
                float4 x0 = xv[4 * q + 0], x1 = xv[4 * q + 1];
                float4 x2 = xv[4 * q + 2], x3 = xv[4 * q + 3];
                a0 = fmaf(e0.x, x0.x, a0); a0 = fmaf(e0.y, x0.y, a0);
                a0 = fmaf(e0.z, x0.z, a0); a0 = fmaf(e0.w, x0.w, a0);
                a1 = fmaf(e1.x, x1.x, a1); a1 = fmaf(e1.y, x1.y, a1);
                a1 = fmaf(e1.z, x1.z, a1); a1 = fmaf(e1.w, x1.w, a1);
                a2 = fmaf(e2.x, x2.x, a2); a2 = fmaf(e2.y, x2.y, a2);
                a2 = fmaf(e2.z, x2.z, a2); a2 = fmaf(e2.w, x2.w, a2);
                a3 = fmaf(e3.x, x3.x, a3); a3 = fmaf(e3.y, x3.y, a3);
                a3 = fmaf(e3.z, x3.z, a3); a3 = fmaf(e3.w, x3.w, a3);
            }
            float s = (a0 + a1) + (a2 + a3);
            if (s > best) { best = s; bi = c; }
        }
#pragma unroll
        for (int d = 1; d < 64; d <<= 1) {
            float ob = __shfl_xor(best, d, 64);
            int   oi = __shfl_xor(bi, d, 64);
            bool  sw = (ob > best) || (ob == best && oi < bi);
            best = sw ? ob : best;
            bi   = sw ? oi : bi;
        }
        if (lane == 0) pidx[r] = (float)bi;
    }
}

// ---------------------------------------------------------------------------
// Combine: gather code row, write quantize + ind, deterministic MSE partial.
__global__ __launch_bounds__(256) void vq_combine(const float* __restrict__ input,
                                                  const float* __restrict__ embedT,
                                                  const float* __restrict__ pidx,
                                                  float* __restrict__ out_q,
                                                  float* __restrict__ out_ind,
                                                  float* __restrict__ partials) {
    __shared__ float wsum[4];
    const int tid = threadIdx.x;
    const int r   = blockIdx.x * 256 + tid;

    int bi = (int)pidx[r];
    out_ind[r] = (float)bi;

    float acc = 0.f;
    {
        const float4* x4 = (const float4*)(input + (size_t)r * DIM);
        const float4* q4 = (const float4*)(embedT + (size_t)bi * DIM);
        float4* o4 = (float4*)(out_q + (size_t)r * DIM);
#pragma unroll
        for (int k = 0; k < 16; ++k) {
            float4 q = q4[k];
            float4 x = x4[k];
            o4[k] = q;
            float dx = q.x - x.x; acc = fmaf(dx, dx, acc);
            dx = q.y - x.y;       acc = fmaf(dx, dx, acc);
            dx = q.z - x.z;       acc = fmaf(dx, dx, acc);
            dx = q.w - x.w;       acc = fmaf(dx, dx, acc);
        }
    }
#pragma unroll
    for (int off = 32; off > 0; off >>= 1) acc += __shfl_down(acc, off, 64);
    if ((tid & 63) == 0) wsum[tid >> 6] = acc;
    __syncthreads();
    if (tid == 0) partials[blockIdx.x] = (wsum[0] + wsum[1]) + (wsum[2] + wsum[3]);
}

// ---------------------------------------------------------------------------
__global__ __launch_bounds__(256) void vq_finalize(const float* __restrict__ partials,
                                                   float* __restrict__ out,
                                                   int out_size) {
    __shared__ float sm[256];
    int t = threadIdx.x;
    float v = partials[t] + partials[t + 256];
    sm[t] = v;
    __syncthreads();
    for (int s = 128; s > 0; s >>= 1) {
        if (t < s) sm[t] += sm[t + s];
        __syncthreads();
    }
    if (t == 0) out[DIFF_OFF] = sm[0] / 8388608.0f;
    if (t == 1 && out_size > NU_OFF) out[NU_OFF] = -1.0f;
}

// ---------------------------------------------------------------------------
extern "C" void kernel_launch(void* const* d_in, const int* in_sizes, int n_in,
                              void* d_out, int out_size, void* d_ws, size_t ws_size,
                              hipStream_t stream) {
    const float* input = (const float*)d_in[0];   // [32,64,64,64]
    const float* embed = (const float*)d_in[1];   // [64,1024]
    float* out = (float*)d_out;
    float* ws  = (float*)d_ws;

    float* hee      = ws + WS_HEE;
    float* embedT   = ws + WS_EMBEDT;
    float* partials = ws + WS_PARTIALS;
    float* pidx     = ws + WS_PIDX;
    int*   counter  = (int*)(ws + WS_COUNTER);
    int*   flaglist = (int*)(ws + WS_FLAGLIST);
    unsigned char* bpk = (unsigned char*)(ws + WS_BPK);

    vq_prep<<<36, 256, 0, stream>>>(embed, embedT, hee, counter, bpk);
    vq_score_mfma<<<1024, 256, 0, stream>>>(input, bpk, hee, pidx, counter, flaglist);
    vq_rescore<<<2048, 64, 0, stream>>>(input, embedT, hee, counter, flaglist, pidx);
    vq_combine<<<512, 256, 0, stream>>>(input, embedT, pidx,
                                        out, out + IND_OFF, partials);
    vq_finalize<<<1, 256, 0, stream>>>(partials, out, out_size);
}

// Round 9
// 113.098 us; speedup vs baseline: 3.1933x; 1.0226x over previous
//
#include <hip/hip_runtime.h>
#include <hip/hip_bf16.h>

// Problem constants (fixed by reference)
#define DIM      64
#define NCODE    1024
#define NROWS    131072          // 32*64*64
#define NTILES   64              // 1024 codes / 16 per MFMA tile
#define TAU      0.006f          // near-tie threshold (covers screen+mask error 4x)
#define TSTRIDE  4160            // packed tile: 64B hee + 4x1024B fragments

typedef __attribute__((ext_vector_type(8))) short  short8;  // 8 bf16 (4 VGPRs)
typedef __attribute__((ext_vector_type(4))) float  f32x4;

// Output layout (concatenated in reference return order, all f32):
#define DIFF_OFF 8388608
#define IND_OFF  8388609
#define NU_OFF   (8388609 + 131072)

// ws layout (float offsets)
#define WS_HEE      0            // 1024
#define WS_EMBEDT   1024         // 65536
#define WS_PARTIALS 66560        // 512
#define WS_PIDX     67072        // 131072
#define WS_COUNTER  198144       // 1 (int)
#define WS_FLAGLIST 198145       // 131072 (int)
#define WS_BPK      329220       // 66560 floats = 260 KiB packed codebook

__device__ __forceinline__ unsigned short bf16rn(float f) {
    unsigned int u = __float_as_uint(f);
    return (unsigned short)((u + 0x7FFFu + ((u >> 16) & 1u)) >> 16);
}
__device__ __forceinline__ float bf16tof(unsigned short h) {
    return __uint_as_float(((unsigned int)h) << 16);
}
__device__ __forceinline__ unsigned umin_(unsigned a, unsigned b) { return a < b ? a : b; }
__device__ __forceinline__ unsigned umax_(unsigned a, unsigned b) { return a > b ? a : b; }

// ---------------------------------------------------------------------------
// Fused prep (blocks 0..3) + codebook pack (blocks 4..35).
// prep: embedT[c][d] = embed[d][c]; hee[c] = 0.5*||e_c||^2; zero counter.
// pack: tile ct -> TSTRIDE bytes at ct*TSTRIDE:
//   +0:   16 floats hee (code ct*16+lc)
//   +64:  kstep0 hi | +1088 kstep1 hi | +2112 kstep0 lo | +3136 kstep1 lo
//   lane l: 16B = 8 bf16 of code ct*16+(l&15), k = base+(l>>4)*8 .. +7
__global__ __launch_bounds__(256) void vq_prep(const float* __restrict__ embed,
                                               float* __restrict__ embedT,
                                               float* __restrict__ hee,
                                               int* __restrict__ counter,
                                               unsigned char* __restrict__ bpk) {
    if (blockIdx.x < 4) {
        int c = blockIdx.x * 256 + threadIdx.x;      // 0..1023
        if (c == 0) *counter = 0;
        float s = 0.f;
#pragma unroll
        for (int d = 0; d < DIM; ++d) {
            float v = embed[d * NCODE + c];
            embedT[c * DIM + d] = v;
            s = fmaf(v, v, s);
        }
        hee[c] = 0.5f * s;
    } else {
        int t  = (blockIdx.x - 4) * 256 + threadIdx.x;   // 0..8191
        int s  = t & 1;
        int l  = (t >> 1) & 63;
        int ct = t >> 7;
        int c  = ct * 16 + (l & 15);
        int kb = s * 32 + (l >> 4) * 8;

        unsigned int hw[4], lw[4];
#pragma unroll
        for (int w = 0; w < 4; ++w) {
            float v0 = embed[(kb + 2 * w)     * NCODE + c];
            float v1 = embed[(kb + 2 * w + 1) * NCODE + c];
            unsigned short h0 = bf16rn(v0), h1 = bf16rn(v1);
            unsigned short l0 = bf16rn(v0 - bf16tof(h0));
            unsigned short l1 = bf16rn(v1 - bf16tof(h1));
            hw[w] = (unsigned int)h0 | ((unsigned int)h1 << 16);
            lw[w] = (unsigned int)l0 | ((unsigned int)l1 << 16);
        }
        uint4* dst_h = (uint4*)(bpk + ct * TSTRIDE + 64 + s * 1024 + l * 16);
        uint4* dst_l = (uint4*)(bpk + ct * TSTRIDE + 64 + s * 1024 + l * 16 + 2048);
        *dst_h = make_uint4(hw[0], hw[1], hw[2], hw[3]);
        *dst_l = make_uint4(lw[0], lw[1], lw[2], lw[3]);
        // hee embedded in tile: threads (s==0, l<16) compute it directly.
        if (s == 0 && l < 16) {
            float ss = 0.f;
#pragma unroll
            for (int d = 0; d < DIM; ++d) {
                float v = embed[d * NCODE + c];
                ss = fmaf(v, v, ss);
            }
            *(float*)(bpk + ct * TSTRIDE + l * 4) = 0.5f * ss;
        }
    }
}

// ---------------------------------------------------------------------------
// MFMA scoring v4: distance-form packed-u32 selection + unroll-2 ping-pong
// register buffers (kills 17 copies/iter) + hee embedded in tile (one
// strength-reduced base, 13-bit immediate offsets; kills the hee gather).
__global__ __launch_bounds__(256, 4) void vq_score_mfma(const float* __restrict__ input,
                                                        const unsigned char* __restrict__ bpk,
                                                        float* __restrict__ pidx,
                                                        int* __restrict__ counter,
                                                        int* __restrict__ flaglist) {
    const int tid   = threadIdx.x;
    const int wid   = tid >> 6;
    const int lane  = tid & 63;
    const int g     = lane >> 4;          // k-group / D-row group
    const int lc    = lane & 15;          // A-row within set / D-col (code)
    const int rbase = (blockIdx.x * 4 + wid) * 32;

    // Build A fragments (NEGATED x, hi+lo bf16) and per-slot hx = 0.5||x||^2+1.
    short8 ah[2][2], al[2][2];
    float  hx[2][4];
#pragma unroll
    for (int m = 0; m < 2; ++m) {
        float ssum = 0.f;
#pragma unroll
        for (int s = 0; s < 2; ++s) {
            const float* xr = input + (size_t)(rbase + m * 16 + lc) * DIM + s * 32 + g * 8;
            float4 f0 = *(const float4*)(xr);
            float4 f1 = *(const float4*)(xr + 4);
            float xf[8] = {f0.x, f0.y, f0.z, f0.w, f1.x, f1.y, f1.z, f1.w};
            short8 h8, l8;
#pragma unroll
            for (int j = 0; j < 8; ++j) {
                ssum = fmaf(xf[j], xf[j], ssum);
                float nx = -xf[j];
                unsigned short hb = bf16rn(nx);
                h8[j] = (short)hb;
                l8[j] = (short)bf16rn(nx - bf16tof(hb));
            }
            ah[m][s] = h8;
            al[m][s] = l8;
        }
        ssum += __shfl_xor(ssum, 16, 64);
        ssum += __shfl_xor(ssum, 32, 64);
#pragma unroll
        for (int j = 0; j < 4; ++j)
            hx[m][j] = 0.5f * __shfl(ssum, g * 4 + j, 64) + 1.0f;
    }

    unsigned m1[8], m2[8];
#pragma unroll
    for (int t = 0; t < 8; ++t) { m1[t] = 0xFFFFFFFFu; m2[t] = 0xFFFFFFFFu; }

    // Tile loaders / compute (identical per-tile math as round 8: same acc
    // init order chh+hx, same MFMA sequence, same packed select).
    const unsigned char* fb = bpk + lane * 16 + 64;   // fragment base (lane)
    const unsigned char* hb = bpk + lc * 4;           // hee base (lane)

#define LOADT(T, C0, C1, C2, C3, HH)                                          \
    {   const unsigned char* tp = fb + (T) * TSTRIDE;                         \
        C0 = *(const short8*)(tp);                                            \
        C1 = *(const short8*)(tp + 1024);                                     \
        C2 = *(const short8*)(tp + 2048);                                     \
        C3 = *(const short8*)(tp + 3072);                                     \
        HH = *(const float*)(hb + (T) * TSTRIDE); }

#define COMPT(T, C0, C1, C2, C3, HH)                                          \
    {   _Pragma("unroll")                                                     \
        for (int m = 0; m < 2; ++m) {                                         \
            f32x4 acc = {HH + hx[m][0], HH + hx[m][1],                        \
                         HH + hx[m][2], HH + hx[m][3]};                       \
            acc = __builtin_amdgcn_mfma_f32_16x16x32_bf16(ah[m][0], C0, acc, 0, 0, 0); \
            acc = __builtin_amdgcn_mfma_f32_16x16x32_bf16(al[m][0], C0, acc, 0, 0, 0); \
            acc = __builtin_amdgcn_mfma_f32_16x16x32_bf16(ah[m][0], C2, acc, 0, 0, 0); \
            acc = __builtin_amdgcn_mfma_f32_16x16x32_bf16(ah[m][1], C1, acc, 0, 0, 0); \
            acc = __builtin_amdgcn_mfma_f32_16x16x32_bf16(al[m][1], C1, acc, 0, 0, 0); \
            acc = __builtin_amdgcn_mfma_f32_16x16x32_bf16(ah[m][1], C3, acc, 0, 0, 0); \
            _Pragma("unroll")                                                 \
            for (int j = 0; j < 4; ++j) {                                     \
                unsigned bits = __float_as_uint(acc[j]);                      \
                unsigned pk   = (bits & 0xFFFFFFC0u) | (unsigned)(T);         \
                int s = m * 4 + j;                                            \
                m2[s] = umin_(m2[s], umax_(pk, m1[s]));                       \
                m1[s] = umin_(m1[s], pk);                                     \
            }                                                                 \
        } }

    short8 a0, a1, a2, a3;  float ahh;   // ping
    short8 b0, b1, b2, b3;  float bhh;   // pong

    LOADT(0, a0, a1, a2, a3, ahh);
    for (int ct = 0; ct < NTILES - 2; ct += 2) {
        LOADT(ct + 1, b0, b1, b2, b3, bhh);
        COMPT(ct, a0, a1, a2, a3, ahh);
        LOADT(ct + 2, a0, a1, a2, a3, ahh);
        COMPT(ct + 1, b0, b1, b2, b3, bhh);
    }
    LOADT(NTILES - 1, b0, b1, b2, b3, bhh);
    COMPT(NTILES - 2, a0, a1, a2, a3, ahh);
    COMPT(NTILES - 1, b0, b1, b2, b3, bhh);

#undef LOADT
#undef COMPT

    // Cross-lane merge within each 16-lane group (same g => same rows).
#pragma unroll
    for (int m = 0; m < 2; ++m) {
#pragma unroll
        for (int j = 0; j < 4; ++j) {
            int s = m * 4 + j;
            unsigned v1 = m1[s], v2 = m2[s];
            int ii = (int)(((v1 & 63u) << 4) | (unsigned)lc);   // full code
#pragma unroll
            for (int d = 1; d < 16; d <<= 1) {
                unsigned o1 = __shfl_xor(v1, d, 64);
                int      oi = __shfl_xor(ii, d, 64);
                unsigned o2 = __shfl_xor(v2, d, 64);
                bool sw = (o1 < v1) || (o1 == v1 && oi < ii);
                unsigned losing = sw ? v1 : o1;
                v2 = umin_(umin_(v2, o2), losing);
                v1 = sw ? o1 : v1;
                ii = sw ? oi : ii;
            }
            if (lc == 0) {
                int r = rbase + m * 16 + g * 4 + j;
                pidx[r] = (float)ii;
                float gap = __uint_as_float(v2 & 0xFFFFFFC0u)
                          - __uint_as_float(v1 & 0xFFFFFFC0u);
                if (gap < TAU) {
                    int p = atomicAdd(counter, 1);
                    flaglist[p] = r;
                }
            }
        }
    }
}

// ---------------------------------------------------------------------------
// Exact rescore, 2 flagged rows per embedT sweep (halves the ~900 MB L2
// re-stream). Per-row math is the bit-identical 4-chain f32 formula; result
// per row is independent of pairing -> deterministic despite atomic ordering.
__global__ __launch_bounds__(64) void vq_rescore(const float* __restrict__ input,
                                                 const float* __restrict__ embedT,
                                                 const float* __restrict__ hee,
                                                 const int* __restrict__ counter,
                                                 const int* __restrict__ flaglist,
                                                 float* __restrict__ pidx) {
    const int lane = threadIdx.x;
    const int cnt  = *counter;
    for (int i = blockIdx.x * 2; i < cnt; i += gridDim.x * 2) {
        const int r0 = flaglist[i];
        const int r1 = (i + 1 < cnt) ? flaglist[i + 1] : r0;
        float4 xa[16], xb[16];
        {
            const float4* pa = (const float4*)(input + (size_t)r0 * DIM);
            const float4* pb = (const float4*)(input + (size_t)r1 * DIM);
#pragma unroll
            for (int k = 0; k < 16; ++k) { xa[k] = pa[k]; xb[k] = pb[k]; }
        }
        float bestA = -3.402823466e+38f, bestB = -3.402823466e+38f;
        int   biA = 0, biB = 0;
#pragma unroll 1
        for (int k = 0; k < 16; ++k) {
            int c = lane * 16 + k;
            const float4* e4 = (const float4*)(embedT + (size_t)c * DIM);
            float hh = hee[c];
            float a0 = -hh, a1 = 0.f, a2 = 0.f, a3 = 0.f;
            float b0 = -hh, b1 = 0.f, b2 = 0.f, b3 = 0.f;
#pragma unroll
            for (int q = 0; q < 4; ++q) {
                float4 e0 = e4[4 * q + 0], e1 = e4[4 * q + 1];
                float4 e2 = e4[4 * q + 2], e3 = e4[4 * q + 3];
                float4 p0 = xa[4 * q + 0], p1 = xa[4 * q + 1];
                float4 p2 = xa[4 * q + 2], p3 = xa[4 * q + 3];
                float4 q0 = xb[4 * q + 0], q1 = xb[4 * q + 1];
                float4 q2 = xb[4 * q + 2], q3 = xb[4 * q + 3];
                a0 = fmaf(e0.x, p0.x, a0); a0 = fmaf(e0.y, p0.y, a0);
                a0 = fmaf(e0.z, p0.z, a0); a0 = fmaf(e0.w, p0.w, a0);
                a1 = fmaf(e1.x, p1.x, a1); a1 = fmaf(e1.y, p1.y, a1);
                a1 = fmaf(e1.z, p1.z, a1); a1 = fmaf(e1.w, p1.w, a1);
                a2 = fmaf(e2.x, p2.x, a2); a2 = fmaf(e2.y, p2.y, a2);
                a2 = fmaf(e2.z, p2.z, a2); a2 = fmaf(e2.w, p2.w, a2);
                a3 = fmaf(e3.x, p3.x, a3); a3 = fmaf(e3.y, p3.y, a3);
                a3 = fmaf(e3.z, p3.z, a3); a3 = fmaf(e3.w, p3.w, a3);
                b0 = fmaf(e0.x, q0.x, b0); b0 = fmaf(e0.y, q0.y, b0);
                b0 = fmaf(e0.z, q0.z, b0); b0 = fmaf(e0.w, q0.w, b0);
                b1 = fmaf(e1.x, q1.x, b1); b1 = fmaf(e1.y, q1.y, b1);
                b1 = fmaf(e1.z, q1.z, b1); b1 = fmaf(e1.w, q1.w, b1);
                b2 = fmaf(e2.x, q2.x, b2); b2 = fmaf(e2.y, q2.y, b2);
                b2 = fmaf(e2.z, q2.z, b2); b2 = fmaf(e2.w, q2.w, b2);
                b3 = fmaf(e3.x, q3.x, b3); b3 = fmaf(e3.y, q3.y, b3);
                b3 = fmaf(e3.z, q3.z, b3); b3 = fmaf(e3.w, q3.w, b3);
            }
            float sA = (a0 + a1) + (a2 + a3);
            float sB = (b0 + b1) + (b2 + b3);
            if (sA > bestA) { bestA = sA; biA = c; }
            if (sB > bestB) { bestB = sB; biB = c; }
        }
#pragma unroll
        for (int d = 1; d < 64; d <<= 1) {
            float oA = __shfl_xor(bestA, d, 64);
            int   iA = __shfl_xor(biA, d, 64);
            bool  sA = (oA > bestA) || (oA == bestA && iA < biA);
            bestA = sA ? oA : bestA;
            biA   = sA ? iA : biA;
            float oB = __shfl_xor(bestB, d, 64);
            int   iB = __shfl_xor(biB, d, 64);
            bool  sB = (oB > bestB) || (oB == bestB && iB < biB);
            bestB = sB ? oB : bestB;
            biB   = sB ? iB : biB;
        }
        if (lane == 0) {
            pidx[r0] = (float)biA;
            pidx[r1] = (float)biB;      // r1==r0 -> same value, harmless
        }
    }
}

// ---------------------------------------------------------------------------
// Combine: gather code row, write quantize + ind, deterministic MSE partial.
__global__ __launch_bounds__(256) void vq_combine(const float* __restrict__ input,
                                                  const float* __restrict__ embedT,
                                                  const float* __restrict__ pidx,
                                                  float* __restrict__ out_q,
                                                  float* __restrict__ out_ind,
                                                  float* __restrict__ partials) {
    __shared__ float wsum[4];
    const int tid = threadIdx.x;
    const int r   = blockIdx.x * 256 + tid;

    int bi = (int)pidx[r];
    out_ind[r] = (float)bi;

    float acc = 0.f;
    {
        const float4* x4 = (const float4*)(input + (size_t)r * DIM);
        const float4* q4 = (const float4*)(embedT + (size_t)bi * DIM);
        float4* o4 = (float4*)(out_q + (size_t)r * DIM);
#pragma unroll
        for (int k = 0; k < 16; ++k) {
            float4 q = q4[k];
            float4 x = x4[k];
            o4[k] = q;
            float dx = q.x - x.x; acc = fmaf(dx, dx, acc);
            dx = q.y - x.y;       acc = fmaf(dx, dx, acc);
            dx = q.z - x.z;       acc = fmaf(dx, dx, acc);
            dx = q.w - x.w;       acc = fmaf(dx, dx, acc);
        }
    }
#pragma unroll
    for (int off = 32; off > 0; off >>= 1) acc += __shfl_down(acc, off, 64);
    if ((tid & 63) == 0) wsum[tid >> 6] = acc;
    __syncthreads();
    if (tid == 0) partials[blockIdx.x] = (wsum[0] + wsum[1]) + (wsum[2] + wsum[3]);
}

// ---------------------------------------------------------------------------
__global__ __launch_bounds__(256) void vq_finalize(const float* __restrict__ partials,
                                                   float* __restrict__ out,
                                                   int out_size) {
    __shared__ float sm[256];
    int t = threadIdx.x;
    float v = partials[t] + partials[t + 256];
    sm[t] = v;
    __syncthreads();
    for (int s = 128; s > 0; s >>= 1) {
        if (t < s) sm[t] += sm[t + s];
        __syncthreads();
    }
    if (t == 0) out[DIFF_OFF] = sm[0] / 8388608.0f;
    if (t == 1 && out_size > NU_OFF) out[NU_OFF] = -1.0f;
}

// ---------------------------------------------------------------------------
extern "C" void kernel_launch(void* const* d_in, const int* in_sizes, int n_in,
                              void* d_out, int out_size, void* d_ws, size_t ws_size,
                              hipStream_t stream) {
    const float* input = (const float*)d_in[0];   // [32,64,64,64]
    const float* embed = (const float*)d_in[1];   // [64,1024]
    float* out = (float*)d_out;
    float* ws  = (float*)d_ws;

    float* hee      = ws + WS_HEE;
    float* embedT   = ws + WS_EMBEDT;
    float* partials = ws + WS_PARTIALS;
    float* pidx     = ws + WS_PIDX;
    int*   counter  = (int*)(ws + WS_COUNTER);
    int*   flaglist = (int*)(ws + WS_FLAGLIST);
    unsigned char* bpk = (unsigned char*)(ws + WS_BPK);

    vq_prep<<<36, 256, 0, stream>>>(embed, embedT, hee, counter, bpk);
    vq_score_mfma<<<1024, 256, 0, stream>>>(input, bpk, pidx, counter, flaglist);
    vq_rescore<<<2048, 64, 0, stream>>>(input, embedT, hee, counter, flaglist, pidx);
    vq_combine<<<512, 256, 0, stream>>>(input, embedT, pidx,
                                        out, out + IND_OFF, partials);
    vq_finalize<<<1, 256, 0, stream>>>(partials, out, out_size);
}

// Round 10
// 112.140 us; speedup vs baseline: 3.2205x; 1.0085x over previous
//
#include <hip/hip_runtime.h>
#include <hip/hip_bf16.h>

// Problem constants (fixed by reference)
#define DIM      64
#define NCODE    1024
#define NROWS    131072          // 32*64*64
#define NTILES   64              // 1024 codes / 16 per MFMA tile
#define TAU      0.006f          // near-tie threshold (covers screen+mask error 4x)
#define TSTRIDE  4160            // packed tile: 64B hee + 4x1024B fragments

typedef __attribute__((ext_vector_type(8))) short  short8;  // 8 bf16 (4 VGPRs)
typedef __attribute__((ext_vector_type(4))) float  f32x4;

// Output layout (concatenated in reference return order, all f32):
#define DIFF_OFF 8388608
#define IND_OFF  8388609
#define NU_OFF   (8388609 + 131072)

// ws layout (float offsets)
#define WS_HEE      0            // 1024
#define WS_EMBEDT   1024         // 65536
#define WS_PARTIALS 66560        // 512
#define WS_PIDX     67072        // 131072
#define WS_COUNTER  198144       // 1 (int)
#define WS_FLAGLIST 198145       // 131072 (int)
#define WS_BPK      329220       // 66560 floats = 260 KiB packed codebook

__device__ __forceinline__ unsigned short bf16rn(float f) {
    unsigned int u = __float_as_uint(f);
    return (unsigned short)((u + 0x7FFFu + ((u >> 16) & 1u)) >> 16);
}
__device__ __forceinline__ float bf16tof(unsigned short h) {
    return __uint_as_float(((unsigned int)h) << 16);
}
__device__ __forceinline__ unsigned umin_(unsigned a, unsigned b) { return a < b ? a : b; }
__device__ __forceinline__ unsigned umax_(unsigned a, unsigned b) { return a > b ? a : b; }

// global -> LDS direct copy, 16B per lane (dest = wave-uniform base + lane*16)
__device__ __forceinline__ void stage16(const void* gsrc, void* ldst) {
    __builtin_amdgcn_global_load_lds(
        (const __attribute__((address_space(1))) unsigned int*)gsrc,
        (__attribute__((address_space(3))) unsigned int*)ldst,
        16, 0, 0);
}

// ---------------------------------------------------------------------------
// Fused prep (blocks 0..3) + codebook pack (blocks 4..35).  (unchanged r9)
__global__ __launch_bounds__(256) void vq_prep(const float* __restrict__ embed,
                                               float* __restrict__ embedT,
                                               float* __restrict__ hee,
                                               int* __restrict__ counter,
                                               unsigned char* __restrict__ bpk) {
    if (blockIdx.x < 4) {
        int c = blockIdx.x * 256 + threadIdx.x;      // 0..1023
        if (c == 0) *counter = 0;
        float s = 0.f;
#pragma unroll
        for (int d = 0; d < DIM; ++d) {
            float v = embed[d * NCODE + c];
            embedT[c * DIM + d] = v;
            s = fmaf(v, v, s);
        }
        hee[c] = 0.5f * s;
    } else {
        int t  = (blockIdx.x - 4) * 256 + threadIdx.x;   // 0..8191
        int s  = t & 1;
        int l  = (t >> 1) & 63;
        int ct = t >> 7;
        int c  = ct * 16 + (l & 15);
        int kb = s * 32 + (l >> 4) * 8;

        unsigned int hw[4], lw[4];
#pragma unroll
        for (int w = 0; w < 4; ++w) {
            float v0 = embed[(kb + 2 * w)     * NCODE + c];
            float v1 = embed[(kb + 2 * w + 1) * NCODE + c];
            unsigned short h0 = bf16rn(v0), h1 = bf16rn(v1);
            unsigned short l0 = bf16rn(v0 - bf16tof(h0));
            unsigned short l1 = bf16rn(v1 - bf16tof(h1));
            hw[w] = (unsigned int)h0 | ((unsigned int)h1 << 16);
            lw[w] = (unsigned int)l0 | ((unsigned int)l1 << 16);
        }
        uint4* dst_h = (uint4*)(bpk + ct * TSTRIDE + 64 + s * 1024 + l * 16);
        uint4* dst_l = (uint4*)(bpk + ct * TSTRIDE + 64 + s * 1024 + l * 16 + 2048);
        *dst_h = make_uint4(hw[0], hw[1], hw[2], hw[3]);
        *dst_l = make_uint4(lw[0], lw[1], lw[2], lw[3]);
        if (s == 0 && l < 16) {
            float ss = 0.f;
#pragma unroll
            for (int d = 0; d < DIM; ++d) {
                float v = embed[d * NCODE + c];
                ss = fmaf(v, v, ss);
            }
            *(float*)(bpk + ct * TSTRIDE + l * 4) = 0.5f * ss;
        }
    }
}

// ---------------------------------------------------------------------------
// MFMA scoring v5: LDS 2-phase staged tiles. All 4 waves of a block consume
// the SAME tile bytes -> stage once per block (global_load_lds, 1 instr/wave
// into its 1KB quarter) into 2x4KB LDS double buffer; ds_read_b128 (~120cyc,
// conflict-free) replaces the per-wave L2 fetch (4x L2 traffic cut + the
// round-9 collapsed-ping-pong latency exposure removed).
__global__ __launch_bounds__(256, 4) void vq_score_mfma(const float* __restrict__ input,
                                                        const unsigned char* __restrict__ bpk,
                                                        float* __restrict__ pidx,
                                                        int* __restrict__ counter,
                                                        int* __restrict__ flaglist) {
    __shared__ __align__(16) unsigned char ltile[2 * 4096];

    const int tid   = threadIdx.x;
    const int wid   = tid >> 6;
    const int lane  = tid & 63;
    const int g     = lane >> 4;          // k-group / D-row group
    const int lc    = lane & 15;          // A-row within set / D-col (code)
    const int rbase = (blockIdx.x * 4 + wid) * 32;

    // Build A fragments (NEGATED x, hi+lo bf16) and per-slot hx = 0.5||x||^2+1.
    short8 ah[2][2], al[2][2];
    float  hx[2][4];
#pragma unroll
    for (int m = 0; m < 2; ++m) {
        float ssum = 0.f;
#pragma unroll
        for (int s = 0; s < 2; ++s) {
            const float* xr = input + (size_t)(rbase + m * 16 + lc) * DIM + s * 32 + g * 8;
            float4 f0 = *(const float4*)(xr);
            float4 f1 = *(const float4*)(xr + 4);
            float xf[8] = {f0.x, f0.y, f0.z, f0.w, f1.x, f1.y, f1.z, f1.w};
            short8 h8, l8;
#pragma unroll
            for (int j = 0; j < 8; ++j) {
                ssum = fmaf(xf[j], xf[j], ssum);
                float nx = -xf[j];
                unsigned short hb = bf16rn(nx);
                h8[j] = (short)hb;
                l8[j] = (short)bf16rn(nx - bf16tof(hb));
            }
            ah[m][s] = h8;
            al[m][s] = l8;
        }
        ssum += __shfl_xor(ssum, 16, 64);
        ssum += __shfl_xor(ssum, 32, 64);
#pragma unroll
        for (int j = 0; j < 4; ++j)
            hx[m][j] = 0.5f * __shfl(ssum, g * 4 + j, 64) + 1.0f;
    }

    unsigned m1[8], m2[8];
#pragma unroll
    for (int t = 0; t < 8; ++t) { m1[t] = 0xFFFFFFFFu; m2[t] = 0xFFFFFFFFu; }

    // Stage tile T's 4KB fragment block: wave wid copies bytes [wid*1024, +1KB).
#define STAGE(T, BOFF)                                                        \
    stage16(bpk + (size_t)(T) * TSTRIDE + 64 + wid * 1024 + lane * 16,        \
            ltile + (BOFF) + wid * 1024);

#define HEEG(T) (*(const float*)(bpk + (size_t)(T) * TSTRIDE + lc * 4))

    // Per-tile compute: identical math sequence to rounds 8/9 (same acc init
    // HH+hx order, same MFMA order, same packed-u32 select) on identical
    // bytes -> bit-identical results/flags.
#define COMPT(T, BOFF, HH)                                                    \
    {   const unsigned char* lb = ltile + (BOFF) + lane * 16;                 \
        short8 C0 = *(const short8*)(lb);                                     \
        short8 C1 = *(const short8*)(lb + 1024);                              \
        short8 C2 = *(const short8*)(lb + 2048);                              \
        short8 C3 = *(const short8*)(lb + 3072);                              \
        _Pragma("unroll")                                                     \
        for (int m = 0; m < 2; ++m) {                                         \
            f32x4 acc = {(HH) + hx[m][0], (HH) + hx[m][1],                    \
                         (HH) + hx[m][2], (HH) + hx[m][3]};                   \
            acc = __builtin_amdgcn_mfma_f32_16x16x32_bf16(ah[m][0], C0, acc, 0, 0, 0); \
            acc = __builtin_amdgcn_mfma_f32_16x16x32_bf16(al[m][0], C0, acc, 0, 0, 0); \
            acc = __builtin_amdgcn_mfma_f32_16x16x32_bf16(ah[m][0], C2, acc, 0, 0, 0); \
            acc = __builtin_amdgcn_mfma_f32_16x16x32_bf16(ah[m][1], C1, acc, 0, 0, 0); \
            acc = __builtin_amdgcn_mfma_f32_16x16x32_bf16(al[m][1], C1, acc, 0, 0, 0); \
            acc = __builtin_amdgcn_mfma_f32_16x16x32_bf16(ah[m][1], C3, acc, 0, 0, 0); \
            _Pragma("unroll")                                                 \
            for (int j = 0; j < 4; ++j) {                                     \
                unsigned bits = __float_as_uint(acc[j]);                      \
                unsigned pk   = (bits & 0xFFFFFFC0u) | (unsigned)(T);         \
                int s = m * 4 + j;                                            \
                m2[s] = umin_(m2[s], umax_(pk, m1[s]));                       \
                m1[s] = umin_(m1[s], pk);                                     \
            }                                                                 \
        } }

    // Prologue: stage tile 0 into buffer A.
    STAGE(0, 0);
    float hhA = HEEG(0);
    __syncthreads();

    for (int ct = 0; ct < NTILES - 2; ct += 2) {
        // phase 1: stage ct+1 -> B, compute ct from A
        STAGE(ct + 1, 4096);
        float hhB = HEEG(ct + 1);
        COMPT(ct, 0, hhA);
        __syncthreads();
        // phase 2: stage ct+2 -> A, compute ct+1 from B
        STAGE(ct + 2, 0);
        hhA = HEEG(ct + 2);
        COMPT(ct + 1, 4096, hhB);
        __syncthreads();
    }
    // Tail: ct = 62,63
    STAGE(NTILES - 1, 4096);
    float hhB = HEEG(NTILES - 1);
    COMPT(NTILES - 2, 0, hhA);
    __syncthreads();
    COMPT(NTILES - 1, 4096, hhB);

#undef STAGE
#undef HEEG
#undef COMPT

    // Cross-lane merge within each 16-lane group (same g => same rows).
#pragma unroll
    for (int m = 0; m < 2; ++m) {
#pragma unroll
        for (int j = 0; j < 4; ++j) {
            int s = m * 4 + j;
            unsigned v1 = m1[s], v2 = m2[s];
            int ii = (int)(((v1 & 63u) << 4) | (unsigned)lc);   // full code
#pragma unroll
            for (int d = 1; d < 16; d <<= 1) {
                unsigned o1 = __shfl_xor(v1, d, 64);
                int      oi = __shfl_xor(ii, d, 64);
                unsigned o2 = __shfl_xor(v2, d, 64);
                bool sw = (o1 < v1) || (o1 == v1 && oi < ii);
                unsigned losing = sw ? v1 : o1;
                v2 = umin_(umin_(v2, o2), losing);
                v1 = sw ? o1 : v1;
                ii = sw ? oi : ii;
            }
            if (lc == 0) {
                int r = rbase + m * 16 + g * 4 + j;
                pidx[r] = (float)ii;
                float gap = __uint_as_float(v2 & 0xFFFFFFC0u)
                          - __uint_as_float(v1 & 0xFFFFFFC0u);
                if (gap < TAU) {
                    int p = atomicAdd(counter, 1);
                    flaglist[p] = r;
                }
            }
        }
    }
}

// ---------------------------------------------------------------------------
// Exact rescore, 2 flagged rows per embedT sweep.  (unchanged r9)
__global__ __launch_bounds__(64) void vq_rescore(const float* __restrict__ input,
                                                 const float* __restrict__ embedT,
                                                 const float* __restrict__ hee,
                                                 const int* __restrict__ counter,
                                                 const int* __restrict__ flaglist,
                                                 float* __restrict__ pidx) {
    const int lane = threadIdx.x;
    const int cnt  = *counter;
    for (int i = blockIdx.x * 2; i < cnt; i += gridDim.x * 2) {
        const int r0 = flaglist[i];
        const int r1 = (i + 1 < cnt) ? flaglist[i + 1] : r0;
        float4 xa[16], xb[16];
        {
            const float4* pa = (const float4*)(input + (size_t)r0 * DIM);
            const float4* pb = (const float4*)(input + (size_t)r1 * DIM);
#pragma unroll
            for (int k = 0; k < 16; ++k) { xa[k] = pa[k]; xb[k] = pb[k]; }
        }
        float bestA = -3.402823466e+38f, bestB = -3.402823466e+38f;
        int   biA = 0, biB = 0;
#pragma unroll 1
        for (int k = 0; k < 16; ++k) {
            int c = lane * 16 + k;
            const float4* e4 = (const float4*)(embedT + (size_t)c * DIM);
            float hh = hee[c];
            float a0 = -hh, a1 = 0.f, a2 = 0.f, a3 = 0.f;
            float b0 = -hh, b1 = 0.f, b2 = 0.f, b3 = 0.f;
#pragma unroll
            for (int q = 0; q < 4; ++q) {
                float4 e0 = e4[4 * q + 0], e1 = e4[4 * q + 1];
                float4 e2 = e4[4 * q + 2], e3 = e4[4 * q + 3];
                float4 p0 = xa[4 * q + 0], p1 = xa[4 * q + 1];
                float4 p2 = xa[4 * q + 2], p3 = xa[4 * q + 3];
                float4 q0 = xb[4 * q + 0], q1 = xb[4 * q + 1];
                float4 q2 = xb[4 * q + 2], q3 = xb[4 * q + 3];
                a0 = fmaf(e0.x, p0.x, a0); a0 = fmaf(e0.y, p0.y, a0);
                a0 = fmaf(e0.z, p0.z, a0); a0 = fmaf(e0.w, p0.w, a0);
                a1 = fmaf(e1.x, p1.x, a1); a1 = fmaf(e1.y, p1.y, a1);
                a1 = fmaf(e1.z, p1.z, a1); a1 = fmaf(e1.w, p1.w, a1);
                a2 = fmaf(e2.x, p2.x, a2); a2 = fmaf(e2.y, p2.y, a2);
                a2 = fmaf(e2.z, p2.z, a2); a2 = fmaf(e2.w, p2.w, a2);
                a3 = fmaf(e3.x, p3.x, a3); a3 = fmaf(e3.y, p3.y, a3);
                a3 = fmaf(e3.z, p3.z, a3); a3 = fmaf(e3.w, p3.w, a3);
                b0 = fmaf(e0.x, q0.x, b0); b0 = fmaf(e0.y, q0.y, b0);
                b0 = fmaf(e0.z, q0.z, b0); b0 = fmaf(e0.w, q0.w, b0);
                b1 = fmaf(e1.x, q1.x, b1); b1 = fmaf(e1.y, q1.y, b1);
                b1 = fmaf(e1.z, q1.z, b1); b1 = fmaf(e1.w, q1.w, b1);
                b2 = fmaf(e2.x, q2.x, b2); b2 = fmaf(e2.y, q2.y, b2);
                b2 = fmaf(e2.z, q2.z, b2); b2 = fmaf(e2.w, q2.w, b2);
                b3 = fmaf(e3.x, q3.x, b3); b3 = fmaf(e3.y, q3.y, b3);
                b3 = fmaf(e3.z, q3.z, b3); b3 = fmaf(e3.w, q3.w, b3);
            }
            float sA = (a0 + a1) + (a2 + a3);
            float sB = (b0 + b1) + (b2 + b3);
            if (sA > bestA) { bestA = sA; biA = c; }
            if (sB > bestB) { bestB = sB; biB = c; }
        }
#pragma unroll
        for (int d = 1; d < 64; d <<= 1) {
            float oA = __shfl_xor(bestA, d, 64);
            int   iA = __shfl_xor(biA, d, 64);
            bool  sA = (oA > bestA) || (oA == bestA && iA < biA);
            bestA = sA ? oA : bestA;
            biA   = sA ? iA : biA;
            float oB = __shfl_xor(bestB, d, 64);
            int   iB = __shfl_xor(biB, d, 64);
            bool  sB = (oB > bestB) || (oB == bestB && iB < biB);
            bestB = sB ? oB : bestB;
            biB   = sB ? iB : biB;
        }
        if (lane == 0) {
            pidx[r0] = (float)biA;
            pidx[r1] = (float)biB;
        }
    }
}

// ---------------------------------------------------------------------------
// Combine: gather code row, write quantize + ind, deterministic MSE partial.
__global__ __launch_bounds__(256) void vq_combine(const float* __restrict__ input,
                                                  const float* __restrict__ embedT,
                                                  const float* __restrict__ pidx,
                                                  float* __restrict__ out_q,
                                                  float* __restrict__ out_ind,
                                                  float* __restrict__ partials) {
    __shared__ float wsum[4];
    const int tid = threadIdx.x;
    const int r   = blockIdx.x * 256 + tid;

    int bi = (int)pidx[r];
    out_ind[r] = (float)bi;

    float acc = 0.f;
    {
        const float4* x4 = (const float4*)(input + (size_t)r * DIM);
        const float4* q4 = (const float4*)(embedT + (size_t)bi * DIM);
        float4* o4 = (float4*)(out_q + (size_t)r * DIM);
#pragma unroll
        for (int k = 0; k < 16; ++k) {
            float4 q = q4[k];
            float4 x = x4[k];
            o4[k] = q;
            float dx = q.x - x.x; acc = fmaf(dx, dx, acc);
            dx = q.y - x.y;       acc = fmaf(dx, dx, acc);
            dx = q.z - x.z;       acc = fmaf(dx, dx, acc);
            dx = q.w - x.w;       acc = fmaf(dx, dx, acc);
        }
    }
#pragma unroll
    for (int off = 32; off > 0; off >>= 1) acc += __shfl_down(acc, off, 64);
    if ((tid & 63) == 0) wsum[tid >> 6] = acc;
    __syncthreads();
    if (tid == 0) partials[blockIdx.x] = (wsum[0] + wsum[1]) + (wsum[2] + wsum[3]);
}

// ---------------------------------------------------------------------------
__global__ __launch_bounds__(256) void vq_finalize(const float* __restrict__ partials,
                                                   float* __restrict__ out,
                                                   int out_size) {
    __shared__ float sm[256];
    int t = threadIdx.x;
    float v = partials[t] + partials[t + 256];
    sm[t] = v;
    __syncthreads();
    for (int s = 128; s > 0; s >>= 1) {
        if (t < s) sm[t] += sm[t + s];
        __syncthreads();
    }
    if (t == 0) out[DIFF_OFF] = sm[0] / 8388608.0f;
    if (t == 1 && out_size > NU_OFF) out[NU_OFF] = -1.0f;
}

// ---------------------------------------------------------------------------
extern "C" void kernel_launch(void* const* d_in, const int* in_sizes, int n_in,
                              void* d_out, int out_size, void* d_ws, size_t ws_size,
                              hipStream_t stream) {
    const float* input = (const float*)d_in[0];   // [32,64,64,64]
    const float* embed = (const float*)d_in[1];   // [64,1024]
    float* out = (float*)d_out;
    float* ws  = (float*)d_ws;

    float* hee      = ws + WS_HEE;
    float* embedT   = ws + WS_EMBEDT;
    float* partials = ws + WS_PARTIALS;
    float* pidx     = ws + WS_PIDX;
    int*   counter  = (int*)(ws + WS_COUNTER);
    int*   flaglist = (int*)(ws + WS_FLAGLIST);
    unsigned char* bpk = (unsigned char*)(ws + WS_BPK);

    vq_prep<<<36, 256, 0, stream>>>(embed, embedT, hee, counter, bpk);
    vq_score_mfma<<<1024, 256, 0, stream>>>(input, bpk, pidx, counter, flaglist);
    vq_rescore<<<2048, 64, 0, stream>>>(input, embedT, hee, counter, flaglist, pidx);
    vq_combine<<<512, 256, 0, stream>>>(input, embedT, pidx,
                                        out, out + IND_OFF, partials);
    vq_finalize<<<1, 256, 0, stream>>>(partials, out, out_size);
}

// Round 12
// 110.313 us; speedup vs baseline: 3.2739x; 1.0166x over previous
//
#include <hip/hip_runtime.h>
#include <hip/hip_bf16.h>

// Problem constants (fixed by reference)
#define DIM      64
#define NCODE    1024
#define NROWS    131072          // 32*64*64
#define NTILES   64              // 1024 codes / 16 per MFMA tile
#define TAU      0.006f          // near-tie threshold (covers screen+mask error 4x)
#define TSTRIDE  4160            // packed tile: 64B hee + 4x1024B fragments

typedef __attribute__((ext_vector_type(8))) short  short8;  // 8 bf16 (4 VGPRs)
typedef __attribute__((ext_vector_type(4))) float  f32x4;

// Output layout (concatenated in reference return order, all f32):
#define DIFF_OFF 8388608
#define IND_OFF  8388609
#define NU_OFF   (8388609 + 131072)

// ws layout (float offsets)
#define WS_HEE      0            // 1024
#define WS_EMBEDT   1024         // 65536
#define WS_PARTIALS 66560        // 512
#define WS_PIDX     67072        // 131072
#define WS_COUNTER  198144       // 1 (int)
#define WS_FLAGLIST 198145       // 131072 (int)
#define WS_BPK      329220       // 66560 floats = 260 KiB packed codebook

__device__ __forceinline__ unsigned short bf16rn(float f) {
    unsigned int u = __float_as_uint(f);
    return (unsigned short)((u + 0x7FFFu + ((u >> 16) & 1u)) >> 16);
}
__device__ __forceinline__ float bf16tof(unsigned short h) {
    return __uint_as_float(((unsigned int)h) << 16);
}
__device__ __forceinline__ unsigned umin_(unsigned a, unsigned b) { return a < b ? a : b; }
__device__ __forceinline__ unsigned umax_(unsigned a, unsigned b) { return a > b ? a : b; }

// ---------------------------------------------------------------------------
// Fused prep (blocks 0..3) + codebook pack (blocks 4..35).  (unchanged r9/r10)
__global__ __launch_bounds__(256) void vq_prep(const float* __restrict__ embed,
                                               float* __restrict__ embedT,
                                               float* __restrict__ hee,
                                               int* __restrict__ counter,
                                               unsigned char* __restrict__ bpk) {
    if (blockIdx.x < 4) {
        int c = blockIdx.x * 256 + threadIdx.x;      // 0..1023
        if (c == 0) *counter = 0;
        float s = 0.f;
#pragma unroll
        for (int d = 0; d < DIM; ++d) {
            float v = embed[d * NCODE + c];
            embedT[c * DIM + d] = v;
            s = fmaf(v, v, s);
        }
        hee[c] = 0.5f * s;
    } else {
        int t  = (blockIdx.x - 4) * 256 + threadIdx.x;   // 0..8191
        int s  = t & 1;
        int l  = (t >> 1) & 63;
        int ct = t >> 7;
        int c  = ct * 16 + (l & 15);
        int kb = s * 32 + (l >> 4) * 8;

        unsigned int hw[4], lw[4];
#pragma unroll
        for (int w = 0; w < 4; ++w) {
            float v0 = embed[(kb + 2 * w)     * NCODE + c];
            float v1 = embed[(kb + 2 * w + 1) * NCODE + c];
            unsigned short h0 = bf16rn(v0), h1 = bf16rn(v1);
            unsigned short l0 = bf16rn(v0 - bf16tof(h0));
            unsigned short l1 = bf16rn(v1 - bf16tof(h1));
            hw[w] = (unsigned int)h0 | ((unsigned int)h1 << 16);
            lw[w] = (unsigned int)l0 | ((unsigned int)l1 << 16);
        }
        uint4* dst_h = (uint4*)(bpk + ct * TSTRIDE + 64 + s * 1024 + l * 16);
        uint4* dst_l = (uint4*)(bpk + ct * TSTRIDE + 64 + s * 1024 + l * 16 + 2048);
        *dst_h = make_uint4(hw[0], hw[1], hw[2], hw[3]);
        *dst_l = make_uint4(lw[0], lw[1], lw[2], lw[3]);
        if (s == 0 && l < 16) {
            float ss = 0.f;
#pragma unroll
            for (int d = 0; d < DIM; ++d) {
                float v = embed[d * NCODE + c];
                ss = fmaf(v, v, ss);
            }
            *(float*)(bpk + ct * TSTRIDE + l * 4) = 0.5f * ss;
        }
    }
}

// ---------------------------------------------------------------------------
// MFMA scoring v6b: barrier-free per-wave pipeline with counted vmcnt.
// Round-11 compile fix: the wait is a bare s_waitcnt + sched_barrier(0)
// (guide rule #18 — the sched_barrier is what stops hipcc from hoisting the
// register-only MFMAs above the wait; tied vector operands don't compile).
// Volatile asm order pins the load-issue points, so the schedule is:
// issue A, issue B, wait(5)->compute A, issue A', wait(5)->compute B, ...
#define ISSUE_T(C0, C1, C2, C3, HH, FA, HA)                                   \
    asm volatile("global_load_dwordx4 %0, %1, off"             : "=v"(C0) : "v"(FA)); \
    asm volatile("global_load_dwordx4 %0, %1, off offset:1024" : "=v"(C1) : "v"(FA)); \
    asm volatile("global_load_dwordx4 %0, %1, off offset:2048" : "=v"(C2) : "v"(FA)); \
    asm volatile("global_load_dwordx4 %0, %1, off offset:3072" : "=v"(C3) : "v"(FA)); \
    asm volatile("global_load_dword %0, %1, off"               : "=v"(HH) : "v"(HA));

#define WAITN(N)                                                              \
    asm volatile("s_waitcnt vmcnt(" #N ")" ::: "memory");                     \
    __builtin_amdgcn_sched_barrier(0);

__global__ __launch_bounds__(256, 4) void vq_score_mfma(const float* __restrict__ input,
                                                        const unsigned char* __restrict__ bpk,
                                                        float* __restrict__ pidx,
                                                        int* __restrict__ counter,
                                                        int* __restrict__ flaglist) {
    const int tid   = threadIdx.x;
    const int wid   = tid >> 6;
    const int lane  = tid & 63;
    const int g     = lane >> 4;          // k-group / D-row group
    const int lc    = lane & 15;          // A-row within set / D-col (code)
    const int rbase = (blockIdx.x * 4 + wid) * 32;

    // Build A fragments (NEGATED x, hi+lo bf16) and per-slot hx = 0.5||x||^2+1.
    short8 ah[2][2], al[2][2];
    float  hx[2][4];
#pragma unroll
    for (int m = 0; m < 2; ++m) {
        float ssum = 0.f;
#pragma unroll
        for (int s = 0; s < 2; ++s) {
            const float* xr = input + (size_t)(rbase + m * 16 + lc) * DIM + s * 32 + g * 8;
            float4 f0 = *(const float4*)(xr);
            float4 f1 = *(const float4*)(xr + 4);
            float xf[8] = {f0.x, f0.y, f0.z, f0.w, f1.x, f1.y, f1.z, f1.w};
            short8 h8, l8;
#pragma unroll
            for (int j = 0; j < 8; ++j) {
                ssum = fmaf(xf[j], xf[j], ssum);
                float nx = -xf[j];
                unsigned short hb = bf16rn(nx);
                h8[j] = (short)hb;
                l8[j] = (short)bf16rn(nx - bf16tof(hb));
            }
            ah[m][s] = h8;
            al[m][s] = l8;
        }
        ssum += __shfl_xor(ssum, 16, 64);
        ssum += __shfl_xor(ssum, 32, 64);
#pragma unroll
        for (int j = 0; j < 4; ++j)
            hx[m][j] = 0.5f * __shfl(ssum, g * 4 + j, 64) + 1.0f;
    }

    unsigned m1[8], m2[8];
#pragma unroll
    for (int t = 0; t < 8; ++t) { m1[t] = 0xFFFFFFFFu; m2[t] = 0xFFFFFFFFu; }

    // Per-tile compute: identical math sequence to r8-r10 (same acc init
    // HH+hx order, same MFMA order, same packed-u32 select) on identical
    // bytes -> bit-identical results/flags.
#define COMPT(T, C0, C1, C2, C3, HH)                                          \
    {   short8 s0 = __builtin_bit_cast(short8, C0);                           \
        short8 s1 = __builtin_bit_cast(short8, C1);                           \
        short8 s2 = __builtin_bit_cast(short8, C2);                           \
        short8 s3 = __builtin_bit_cast(short8, C3);                           \
        _Pragma("unroll")                                                     \
        for (int m = 0; m < 2; ++m) {                                         \
            f32x4 acc = {(HH) + hx[m][0], (HH) + hx[m][1],                    \
                         (HH) + hx[m][2], (HH) + hx[m][3]};                   \
            acc = __builtin_amdgcn_mfma_f32_16x16x32_bf16(ah[m][0], s0, acc, 0, 0, 0); \
            acc = __builtin_amdgcn_mfma_f32_16x16x32_bf16(al[m][0], s0, acc, 0, 0, 0); \
            acc = __builtin_amdgcn_mfma_f32_16x16x32_bf16(ah[m][0], s2, acc, 0, 0, 0); \
            acc = __builtin_amdgcn_mfma_f32_16x16x32_bf16(ah[m][1], s1, acc, 0, 0, 0); \
            acc = __builtin_amdgcn_mfma_f32_16x16x32_bf16(al[m][1], s1, acc, 0, 0, 0); \
            acc = __builtin_amdgcn_mfma_f32_16x16x32_bf16(ah[m][1], s3, acc, 0, 0, 0); \
            _Pragma("unroll")                                                 \
            for (int j = 0; j < 4; ++j) {                                     \
                unsigned bits = __float_as_uint(acc[j]);                      \
                unsigned pk   = (bits & 0xFFFFFFC0u) | (unsigned)(T);         \
                int s = m * 4 + j;                                            \
                m2[s] = umin_(m2[s], umax_(pk, m1[s]));                       \
                m1[s] = umin_(m1[s], pk);                                     \
            }                                                                 \
        } }

    // Address registers (64-bit VGPR pairs), stepped by 2*TSTRIDE per buffer.
    unsigned long long fA = (unsigned long long)(uintptr_t)(bpk + 64 + lane * 16);
    unsigned long long hA = (unsigned long long)(uintptr_t)(bpk + lc * 4);
    unsigned long long fB = fA + TSTRIDE;
    unsigned long long hB = hA + TSTRIDE;

    uint4 a0, a1, a2, a3;  float ahh;   // ping (even tiles)
    uint4 b0, b1, b2, b3;  float bhh;   // pong (odd tiles)

    ISSUE_T(a0, a1, a2, a3, ahh, fA, hA);            // tile 0 in flight
    fA += 2 * TSTRIDE;  hA += 2 * TSTRIDE;

    for (int ct = 0; ct < NTILES - 2; ct += 2) {
        ISSUE_T(b0, b1, b2, b3, bhh, fB, hB);        // tile ct+1 in flight
        fB += 2 * TSTRIDE;  hB += 2 * TSTRIDE;
        WAITN(5);                                    // tile ct ready; ct+1 in flight
        COMPT(ct, a0, a1, a2, a3, ahh);
        ISSUE_T(a0, a1, a2, a3, ahh, fA, hA);        // tile ct+2 in flight
        fA += 2 * TSTRIDE;  hA += 2 * TSTRIDE;
        WAITN(5);                                    // tile ct+1 ready
        COMPT(ct + 1, b0, b1, b2, b3, bhh);
    }
    // Tail: tiles 62 (in flight in A) and 63.
    ISSUE_T(b0, b1, b2, b3, bhh, fB, hB);
    WAITN(5);
    COMPT(NTILES - 2, a0, a1, a2, a3, ahh);
    WAITN(0);
    COMPT(NTILES - 1, b0, b1, b2, b3, bhh);

#undef COMPT

    // Cross-lane merge within each 16-lane group (same g => same rows).
#pragma unroll
    for (int m = 0; m < 2; ++m) {
#pragma unroll
        for (int j = 0; j < 4; ++j) {
            int s = m * 4 + j;
            unsigned v1 = m1[s], v2 = m2[s];
            int ii = (int)(((v1 & 63u) << 4) | (unsigned)lc);   // full code
#pragma unroll
            for (int d = 1; d < 16; d <<= 1) {
                unsigned o1 = __shfl_xor(v1, d, 64);
                int      oi = __shfl_xor(ii, d, 64);
                unsigned o2 = __shfl_xor(v2, d, 64);
                bool sw = (o1 < v1) || (o1 == v1 && oi < ii);
                unsigned losing = sw ? v1 : o1;
                v2 = umin_(umin_(v2, o2), losing);
                v1 = sw ? o1 : v1;
                ii = sw ? oi : ii;
            }
            if (lc == 0) {
                int r = rbase + m * 16 + g * 4 + j;
                pidx[r] = (float)ii;
                float gap = __uint_as_float(v2 & 0xFFFFFFC0u)
                          - __uint_as_float(v1 & 0xFFFFFFC0u);
                if (gap < TAU) {
                    int p = atomicAdd(counter, 1);
                    flaglist[p] = r;
                }
            }
        }
    }
}

// ---------------------------------------------------------------------------
// Exact rescore, 2 flagged rows per embedT sweep.  (unchanged r9/r10)
__global__ __launch_bounds__(64) void vq_rescore(const float* __restrict__ input,
                                                 const float* __restrict__ embedT,
                                                 const float* __restrict__ hee,
                                                 const int* __restrict__ counter,
                                                 const int* __restrict__ flaglist,
                                                 float* __restrict__ pidx) {
    const int lane = threadIdx.x;
    const int cnt  = *counter;
    for (int i = blockIdx.x * 2; i < cnt; i += gridDim.x * 2) {
        const int r0 = flaglist[i];
        const int r1 = (i + 1 < cnt) ? flaglist[i + 1] : r0;
        float4 xa[16], xb[16];
        {
            const float4* pa = (const float4*)(input + (size_t)r0 * DIM);
            const float4* pb = (const float4*)(input + (size_t)r1 * DIM);
#pragma unroll
            for (int k = 0; k < 16; ++k) { xa[k] = pa[k]; xb[k] = pb[k]; }
        }
        float bestA = -3.402823466e+38f, bestB = -3.402823466e+38f;
        int   biA = 0, biB = 0;
#pragma unroll 1
        for (int k = 0; k < 16; ++k) {
            int c = lane * 16 + k;
            const float4* e4 = (const float4*)(embedT + (size_t)c * DIM);
            float hh = hee[c];
            float a0 = -hh, a1 = 0.f, a2 = 0.f, a3 = 0.f;
            float b0 = -hh, b1 = 0.f, b2 = 0.f, b3 = 0.f;
#pragma unroll
            for (int q = 0; q < 4; ++q) {
                float4 e0 = e4[4 * q + 0], e1 = e4[4 * q + 1];
                float4 e2 = e4[4 * q + 2], e3 = e4[4 * q + 3];
                float4 p0 = xa[4 * q + 0], p1 = xa[4 * q + 1];
                float4 p2 = xa[4 * q + 2], p3 = xa[4 * q + 3];
                float4 q0 = xb[4 * q + 0], q1 = xb[4 * q + 1];
                float4 q2 = xb[4 * q + 2], q3 = xb[4 * q + 3];
                a0 = fmaf(e0.x, p0.x, a0); a0 = fmaf(e0.y, p0.y, a0);
                a0 = fmaf(e0.z, p0.z, a0); a0 = fmaf(e0.w, p0.w, a0);
                a1 = fmaf(e1.x, p1.x, a1); a1 = fmaf(e1.y, p1.y, a1);
                a1 = fmaf(e1.z, p1.z, a1); a1 = fmaf(e1.w, p1.w, a1);
                a2 = fmaf(e2.x, p2.x, a2); a2 = fmaf(e2.y, p2.y, a2);
                a2 = fmaf(e2.z, p2.z, a2); a2 = fmaf(e2.w, p2.w, a2);
                a3 = fmaf(e3.x, p3.x, a3); a3 = fmaf(e3.y, p3.y, a3);
                a3 = fmaf(e3.z, p3.z, a3); a3 = fmaf(e3.w, p3.w, a3);
                b0 = fmaf(e0.x, q0.x, b0); b0 = fmaf(e0.y, q0.y, b0);
                b0 = fmaf(e0.z, q0.z, b0); b0 = fmaf(e0.w, q0.w, b0);
                b1 = fmaf(e1.x, q1.x, b1); b1 = fmaf(e1.y, q1.y, b1);
                b1 = fmaf(e1.z, q1.z, b1); b1 = fmaf(e1.w, q1.w, b1);
                b2 = fmaf(e2.x, q2.x, b2); b2 = fmaf(e2.y, q2.y, b2);
                b2 = fmaf(e2.z, q2.z, b2); b2 = fmaf(e2.w, q2.w, b2);
                b3 = fmaf(e3.x, q3.x, b3); b3 = fmaf(e3.y, q3.y, b3);
                b3 = fmaf(e3.z, q3.z, b3); b3 = fmaf(e3.w, q3.w, b3);
            }
            float sA = (a0 + a1) + (a2 + a3);
            float sB = (b0 + b1) + (b2 + b3);
            if (sA > bestA) { bestA = sA; biA = c; }
            if (sB > bestB) { bestB = sB; biB = c; }
        }
#pragma unroll
        for (int d = 1; d < 64; d <<= 1) {
            float oA = __shfl_xor(bestA, d, 64);
            int   iA = __shfl_xor(biA, d, 64);
            bool  sA = (oA > bestA) || (oA == bestA && iA < biA);
            bestA = sA ? oA : bestA;
            biA   = sA ? iA : biA;
            float oB = __shfl_xor(bestB, d, 64);
            int   iB = __shfl_xor(biB, d, 64);
            bool  sB = (oB > bestB) || (oB == bestB && iB < biB);
            bestB = sB ? oB : bestB;
            biB   = sB ? iB : biB;
        }
        if (lane == 0) {
            pidx[r0] = (float)biA;
            pidx[r1] = (float)biB;
        }
    }
}

// ---------------------------------------------------------------------------
// Combine: gather code row, write quantize + ind, deterministic MSE partial.
__global__ __launch_bounds__(256) void vq_combine(const float* __restrict__ input,
                                                  const float* __restrict__ embedT,
                                                  const float* __restrict__ pidx,
                                                  float* __restrict__ out_q,
                                                  float* __restrict__ out_ind,
                                                  float* __restrict__ partials) {
    __shared__ float wsum[4];
    const int tid = threadIdx.x;
    const int r   = blockIdx.x * 256 + tid;

    int bi = (int)pidx[r];
    out_ind[r] = (float)bi;

    float acc = 0.f;
    {
        const float4* x4 = (const float4*)(input + (size_t)r * DIM);
        const float4* q4 = (const float4*)(embedT + (size_t)bi * DIM);
        float4* o4 = (float4*)(out_q + (size_t)r * DIM);
#pragma unroll
        for (int k = 0; k < 16; ++k) {
            float4 q = q4[k];
            float4 x = x4[k];
            o4[k] = q;
            float dx = q.x - x.x; acc = fmaf(dx, dx, acc);
            dx = q.y - x.y;       acc = fmaf(dx, dx, acc);
            dx = q.z - x.z;       acc = fmaf(dx, dx, acc);
            dx = q.w - x.w;       acc = fmaf(dx, dx, acc);
        }
    }
#pragma unroll
    for (int off = 32; off > 0; off >>= 1) acc += __shfl_down(acc, off, 64);
    if ((tid & 63) == 0) wsum[tid >> 6] = acc;
    __syncthreads();
    if (tid == 0) partials[blockIdx.x] = (wsum[0] + wsum[1]) + (wsum[2] + wsum[3]);
}

// ---------------------------------------------------------------------------
__global__ __launch_bounds__(256) void vq_finalize(const float* __restrict__ partials,
                                                   float* __restrict__ out,
                                                   int out_size) {
    __shared__ float sm[256];
    int t = threadIdx.x;
    float v = partials[t] + partials[t + 256];
    sm[t] = v;
    __syncthreads();
    for (int s = 128; s > 0; s >>= 1) {
        if (t < s) sm[t] += sm[t + s];
        __syncthreads();
    }
    if (t == 0) out[DIFF_OFF] = sm[0] / 8388608.0f;
    if (t == 1 && out_size > NU_OFF) out[NU_OFF] = -1.0f;
}

// ---------------------------------------------------------------------------
extern "C" void kernel_launch(void* const* d_in, const int* in_sizes, int n_in,
                              void* d_out, int out_size, void* d_ws, size_t ws_size,
                              hipStream_t stream) {
    const float* input = (const float*)d_in[0];   // [32,64,64,64]
    const float* embed = (const float*)d_in[1];   // [64,1024]
    float* out = (float*)d_out;
    float* ws  = (float*)d_ws;

    float* hee      = ws + WS_HEE;
    float* embedT   = ws + WS_EMBEDT;
    float* partials = ws + WS_PARTIALS;
    float* pidx     = ws + WS_PIDX;
    int*   counter  = (int*)(ws + WS_COUNTER);
    int*   flaglist = (int*)(ws + WS_FLAGLIST);
    unsigned char* bpk = (unsigned char*)(ws + WS_BPK);

    vq_prep<<<36, 256, 0, stream>>>(embed, embedT, hee, counter, bpk);
    vq_score_mfma<<<1024, 256, 0, stream>>>(input, bpk, pidx, counter, flaglist);
    vq_rescore<<<2048, 64, 0, stream>>>(input, embedT, hee, counter, flaglist, pidx);
    vq_combine<<<512, 256, 0, stream>>>(input, embedT, pidx,
                                        out, out + IND_OFF, partials);
    vq_finalize<<<1, 256, 0, stream>>>(partials, out, out_size);
}

// Round 13
// 98.463 us; speedup vs baseline: 3.6679x; 1.1203x over previous
//
#include <hip/hip_runtime.h>
#include <hip/hip_bf16.h>

// Problem constants (fixed by reference)
#define DIM      64
#define NCODE    1024
#define NROWS    131072          // 32*64*64
#define NTILES   64              // 1024 codes / 16 per MFMA tile
#define TAU      0.006f          // near-tie threshold (covers screen+mask error 4x)
#define TSTRIDE  4160            // packed tile: 64B hee + 4x1024B fragments

typedef __attribute__((ext_vector_type(8))) short  short8;  // 8 bf16 (4 VGPRs)
typedef __attribute__((ext_vector_type(4))) float  f32x4;

// Output layout (concatenated in reference return order, all f32):
#define DIFF_OFF 8388608
#define IND_OFF  8388609
#define NU_OFF   (8388609 + 131072)

// ws layout (float offsets)
#define WS_HEE      0            // 1024
#define WS_EMBEDT   1024         // 65536
#define WS_PARTIALS 66560        // 512
#define WS_RMSE     67072        // 131072 (per-row mse)
#define WS_COUNTER  198144       // 1 (int)
#define WS_FLAGLIST 198145       // 131072 (int)
#define WS_BPK      329220       // 66560 floats = 260 KiB packed codebook

__device__ __forceinline__ unsigned short bf16rn(float f) {
    unsigned int u = __float_as_uint(f);
    return (unsigned short)((u + 0x7FFFu + ((u >> 16) & 1u)) >> 16);
}
__device__ __forceinline__ float bf16tof(unsigned short h) {
    return __uint_as_float(((unsigned int)h) << 16);
}
__device__ __forceinline__ unsigned umin_(unsigned a, unsigned b) { return a < b ? a : b; }
__device__ __forceinline__ unsigned umax_(unsigned a, unsigned b) { return a > b ? a : b; }

// ---------------------------------------------------------------------------
// Fused prep (blocks 0..3) + codebook pack (blocks 4..35).  (unchanged)
__global__ __launch_bounds__(256) void vq_prep(const float* __restrict__ embed,
                                               float* __restrict__ embedT,
                                               float* __restrict__ hee,
                                               int* __restrict__ counter,
                                               unsigned char* __restrict__ bpk) {
    if (blockIdx.x < 4) {
        int c = blockIdx.x * 256 + threadIdx.x;      // 0..1023
        if (c == 0) *counter = 0;
        float s = 0.f;
#pragma unroll
        for (int d = 0; d < DIM; ++d) {
            float v = embed[d * NCODE + c];
            embedT[c * DIM + d] = v;
            s = fmaf(v, v, s);
        }
        hee[c] = 0.5f * s;
    } else {
        int t  = (blockIdx.x - 4) * 256 + threadIdx.x;   // 0..8191
        int s  = t & 1;
        int l  = (t >> 1) & 63;
        int ct = t >> 7;
        int c  = ct * 16 + (l & 15);
        int kb = s * 32 + (l >> 4) * 8;

        unsigned int hw[4], lw[4];
#pragma unroll
        for (int w = 0; w < 4; ++w) {
            float v0 = embed[(kb + 2 * w)     * NCODE + c];
            float v1 = embed[(kb + 2 * w + 1) * NCODE + c];
            unsigned short h0 = bf16rn(v0), h1 = bf16rn(v1);
            unsigned short l0 = bf16rn(v0 - bf16tof(h0));
            unsigned short l1 = bf16rn(v1 - bf16tof(h1));
            hw[w] = (unsigned int)h0 | ((unsigned int)h1 << 16);
            lw[w] = (unsigned int)l0 | ((unsigned int)l1 << 16);
        }
        uint4* dst_h = (uint4*)(bpk + ct * TSTRIDE + 64 + s * 1024 + l * 16);
        uint4* dst_l = (uint4*)(bpk + ct * TSTRIDE + 64 + s * 1024 + l * 16 + 2048);
        *dst_h = make_uint4(hw[0], hw[1], hw[2], hw[3]);
        *dst_l = make_uint4(lw[0], lw[1], lw[2], lw[3]);
        if (s == 0 && l < 16) {
            float ss = 0.f;
#pragma unroll
            for (int d = 0; d < DIM; ++d) {
                float v = embed[d * NCODE + c];
                ss = fmaf(v, v, ss);
            }
            *(float*)(bpk + ct * TSTRIDE + l * 4) = 0.5f * ss;
        }
    }
}

// ---------------------------------------------------------------------------
// MFMA scoring v7: r12's measured pipeline (unchanged main loop math) +
//  (a) T5 setprio around each 6-MFMA chain;
//  (b) FUSED epilogue: writes quantize (embedT gather via per-wave LDS code
//      table), ind, and row_mse = 2*(d_best-1) directly — the 75MB combine
//      kernel is replaced by a 0.5MB reduction. Flagged rows are later
//      overwritten by vq_rescore (exact f32), selection unchanged.
#define ISSUE_T(C0, C1, C2, C3, HH, FA, HA)                                   \
    asm volatile("global_load_dwordx4 %0, %1, off"             : "=v"(C0) : "v"(FA)); \
    asm volatile("global_load_dwordx4 %0, %1, off offset:1024" : "=v"(C1) : "v"(FA)); \
    asm volatile("global_load_dwordx4 %0, %1, off offset:2048" : "=v"(C2) : "v"(FA)); \
    asm volatile("global_load_dwordx4 %0, %1, off offset:3072" : "=v"(C3) : "v"(FA)); \
    asm volatile("global_load_dword %0, %1, off"               : "=v"(HH) : "v"(HA));

#define WAITN(N)                                                              \
    asm volatile("s_waitcnt vmcnt(" #N ")" ::: "memory");                     \
    __builtin_amdgcn_sched_barrier(0);

__global__ __launch_bounds__(256, 4) void vq_score_mfma(const float* __restrict__ input,
                                                        const unsigned char* __restrict__ bpk,
                                                        const float* __restrict__ embedT,
                                                        float* __restrict__ out_q,
                                                        float* __restrict__ out_ind,
                                                        float* __restrict__ row_mse,
                                                        int* __restrict__ counter,
                                                        int* __restrict__ flaglist) {
    __shared__ int scode[4][32];

    const int tid   = threadIdx.x;
    const int wid   = tid >> 6;
    const int lane  = tid & 63;
    const int g     = lane >> 4;          // k-group / D-row group
    const int lc    = lane & 15;          // A-row within set / D-col (code)
    const int rbase = (blockIdx.x * 4 + wid) * 32;

    // Build A fragments (NEGATED x, hi+lo bf16) and per-slot hx = 0.5||x||^2+1.
    short8 ah[2][2], al[2][2];
    float  hx[2][4];
#pragma unroll
    for (int m = 0; m < 2; ++m) {
        float ssum = 0.f;
#pragma unroll
        for (int s = 0; s < 2; ++s) {
            const float* xr = input + (size_t)(rbase + m * 16 + lc) * DIM + s * 32 + g * 8;
            float4 f0 = *(const float4*)(xr);
            float4 f1 = *(const float4*)(xr + 4);
            float xf[8] = {f0.x, f0.y, f0.z, f0.w, f1.x, f1.y, f1.z, f1.w};
            short8 h8, l8;
#pragma unroll
            for (int j = 0; j < 8; ++j) {
                ssum = fmaf(xf[j], xf[j], ssum);
                float nx = -xf[j];
                unsigned short hb = bf16rn(nx);
                h8[j] = (short)hb;
                l8[j] = (short)bf16rn(nx - bf16tof(hb));
            }
            ah[m][s] = h8;
            al[m][s] = l8;
        }
        ssum += __shfl_xor(ssum, 16, 64);
        ssum += __shfl_xor(ssum, 32, 64);
#pragma unroll
        for (int j = 0; j < 4; ++j)
            hx[m][j] = 0.5f * __shfl(ssum, g * 4 + j, 64) + 1.0f;
    }

    unsigned m1[8], m2[8];
#pragma unroll
    for (int t = 0; t < 8; ++t) { m1[t] = 0xFFFFFFFFu; m2[t] = 0xFFFFFFFFu; }

    // Per-tile compute: identical math sequence to r8-r12 (same acc init
    // HH+hx order, same MFMA order, same packed-u32 select) on identical
    // bytes -> bit-identical results/flags. setprio(1) wraps each MFMA chain.
#define COMPT(T, C0, C1, C2, C3, HH)                                          \
    {   short8 s0 = __builtin_bit_cast(short8, C0);                           \
        short8 s1 = __builtin_bit_cast(short8, C1);                           \
        short8 s2 = __builtin_bit_cast(short8, C2);                           \
        short8 s3 = __builtin_bit_cast(short8, C3);                           \
        _Pragma("unroll")                                                     \
        for (int m = 0; m < 2; ++m) {                                         \
            f32x4 acc = {(HH) + hx[m][0], (HH) + hx[m][1],                    \
                         (HH) + hx[m][2], (HH) + hx[m][3]};                   \
            __builtin_amdgcn_s_setprio(1);                                    \
            acc = __builtin_amdgcn_mfma_f32_16x16x32_bf16(ah[m][0], s0, acc, 0, 0, 0); \
            acc = __builtin_amdgcn_mfma_f32_16x16x32_bf16(al[m][0], s0, acc, 0, 0, 0); \
            acc = __builtin_amdgcn_mfma_f32_16x16x32_bf16(ah[m][0], s2, acc, 0, 0, 0); \
            acc = __builtin_amdgcn_mfma_f32_16x16x32_bf16(ah[m][1], s1, acc, 0, 0, 0); \
            acc = __builtin_amdgcn_mfma_f32_16x16x32_bf16(al[m][1], s1, acc, 0, 0, 0); \
            acc = __builtin_amdgcn_mfma_f32_16x16x32_bf16(ah[m][1], s3, acc, 0, 0, 0); \
            __builtin_amdgcn_s_setprio(0);                                    \
            _Pragma("unroll")                                                 \
            for (int j = 0; j < 4; ++j) {                                     \
                unsigned bits = __float_as_uint(acc[j]);                      \
                unsigned pk   = (bits & 0xFFFFFFC0u) | (unsigned)(T);         \
                int s = m * 4 + j;                                            \
                m2[s] = umin_(m2[s], umax_(pk, m1[s]));                       \
                m1[s] = umin_(m1[s], pk);                                     \
            }                                                                 \
        } }

    // Address registers, stepped by 2*TSTRIDE per buffer.
    unsigned long long fA = (unsigned long long)(uintptr_t)(bpk + 64 + lane * 16);
    unsigned long long hA = (unsigned long long)(uintptr_t)(bpk + lc * 4);
    unsigned long long fB = fA + TSTRIDE;
    unsigned long long hB = hA + TSTRIDE;

    uint4 a0, a1, a2, a3;  float ahh;   // ping (even tiles)
    uint4 b0, b1, b2, b3;  float bhh;   // pong (odd tiles)

    ISSUE_T(a0, a1, a2, a3, ahh, fA, hA);            // tile 0 in flight
    fA += 2 * TSTRIDE;  hA += 2 * TSTRIDE;

    for (int ct = 0; ct < NTILES - 2; ct += 2) {
        ISSUE_T(b0, b1, b2, b3, bhh, fB, hB);        // tile ct+1 in flight
        fB += 2 * TSTRIDE;  hB += 2 * TSTRIDE;
        WAITN(5);                                    // tile ct ready; ct+1 in flight
        COMPT(ct, a0, a1, a2, a3, ahh);
        ISSUE_T(a0, a1, a2, a3, ahh, fA, hA);        // tile ct+2 in flight
        fA += 2 * TSTRIDE;  hA += 2 * TSTRIDE;
        WAITN(5);                                    // tile ct+1 ready
        COMPT(ct + 1, b0, b1, b2, b3, bhh);
    }
    // Tail: tiles 62 (in flight in A) and 63.
    ISSUE_T(b0, b1, b2, b3, bhh, fB, hB);
    WAITN(5);
    COMPT(NTILES - 2, a0, a1, a2, a3, ahh);
    WAITN(0);
    COMPT(NTILES - 1, b0, b1, b2, b3, bhh);

#undef COMPT

    // Cross-lane merge within each 16-lane group (same g => same rows).
#pragma unroll
    for (int m = 0; m < 2; ++m) {
#pragma unroll
        for (int j = 0; j < 4; ++j) {
            int s = m * 4 + j;
            unsigned v1 = m1[s], v2 = m2[s];
            int ii = (int)(((v1 & 63u) << 4) | (unsigned)lc);   // full code
#pragma unroll
            for (int d = 1; d < 16; d <<= 1) {
                unsigned o1 = __shfl_xor(v1, d, 64);
                int      oi = __shfl_xor(ii, d, 64);
                unsigned o2 = __shfl_xor(v2, d, 64);
                bool sw = (o1 < v1) || (o1 == v1 && oi < ii);
                unsigned losing = sw ? v1 : o1;
                v2 = umin_(umin_(v2, o2), losing);
                v1 = sw ? o1 : v1;
                ii = sw ? oi : ii;
            }
            if (lc == 0) {
                int rr = m * 16 + g * 4 + j;        // row within wave (0..31)
                int r  = rbase + rr;
                scode[wid][rr] = ii;
                out_ind[r] = (float)ii;
                // mse estimate from the masked distance: mse = 2*(d-1).
                row_mse[r] = 2.0f * (__uint_as_float(v1 & 0xFFFFFFC0u) - 1.0f);
                float gap = __uint_as_float(v2 & 0xFFFFFFC0u)
                          - __uint_as_float(v1 & 0xFFFFFFC0u);
                if (gap < TAU) {
                    int p = atomicAdd(counter, 1);
                    flaglist[p] = r;
                }
            }
        }
    }

    // Fused quantize write: 2 lanes per row, 8 float4 each (gather L2-hot embedT).
    __syncthreads();
    {
        int r2   = lane >> 1;                        // row within wave
        int code = scode[wid][r2];
        const float4* src = (const float4*)(embedT + (size_t)code * DIM) + (lane & 1) * 8;
        float4*       dst = (float4*)(out_q + (size_t)(rbase + r2) * DIM) + (lane & 1) * 8;
#pragma unroll
        for (int k = 0; k < 8; ++k) dst[k] = src[k];
    }
}

// ---------------------------------------------------------------------------
// Exact rescore, 2 flagged rows per embedT sweep; now also rewrites the
// quantize rows, ind, and exact row_mse (= ||x||^2 - 2*s_best) in place.
__global__ __launch_bounds__(64) void vq_rescore(const float* __restrict__ input,
                                                 const float* __restrict__ embedT,
                                                 const float* __restrict__ hee,
                                                 const int* __restrict__ counter,
                                                 const int* __restrict__ flaglist,
                                                 float* __restrict__ out_q,
                                                 float* __restrict__ out_ind,
                                                 float* __restrict__ row_mse) {
    const int lane = threadIdx.x;
    const int cnt  = *counter;
    for (int i = blockIdx.x * 2; i < cnt; i += gridDim.x * 2) {
        const int r0 = flaglist[i];
        const int r1 = (i + 1 < cnt) ? flaglist[i + 1] : r0;
        float4 xa[16], xb[16];
        float ssA = 0.f, ssB = 0.f;
        {
            const float4* pa = (const float4*)(input + (size_t)r0 * DIM);
            const float4* pb = (const float4*)(input + (size_t)r1 * DIM);
#pragma unroll
            for (int k = 0; k < 16; ++k) {
                xa[k] = pa[k]; xb[k] = pb[k];
                ssA = fmaf(xa[k].x, xa[k].x, ssA); ssA = fmaf(xa[k].y, xa[k].y, ssA);
                ssA = fmaf(xa[k].z, xa[k].z, ssA); ssA = fmaf(xa[k].w, xa[k].w, ssA);
                ssB = fmaf(xb[k].x, xb[k].x, ssB); ssB = fmaf(xb[k].y, xb[k].y, ssB);
                ssB = fmaf(xb[k].z, xb[k].z, ssB); ssB = fmaf(xb[k].w, xb[k].w, ssB);
            }
        }
        float bestA = -3.402823466e+38f, bestB = -3.402823466e+38f;
        int   biA = 0, biB = 0;
#pragma unroll 1
        for (int k = 0; k < 16; ++k) {
            int c = lane * 16 + k;
            const float4* e4 = (const float4*)(embedT + (size_t)c * DIM);
            float hh = hee[c];
            float a0 = -hh, a1 = 0.f, a2 = 0.f, a3 = 0.f;
            float b0 = -hh, b1 = 0.f, b2 = 0.f, b3 = 0.f;
#pragma unroll
            for (int q = 0; q < 4; ++q) {
                float4 e0 = e4[4 * q + 0], e1 = e4[4 * q + 1];
                float4 e2 = e4[4 * q + 2], e3 = e4[4 * q + 3];
                float4 p0 = xa[4 * q + 0], p1 = xa[4 * q + 1];
                float4 p2 = xa[4 * q + 2], p3 = xa[4 * q + 3];
                float4 q0 = xb[4 * q + 0], q1 = xb[4 * q + 1];
                float4 q2 = xb[4 * q + 2], q3 = xb[4 * q + 3];
                a0 = fmaf(e0.x, p0.x, a0); a0 = fmaf(e0.y, p0.y, a0);
                a0 = fmaf(e0.z, p0.z, a0); a0 = fmaf(e0.w, p0.w, a0);
                a1 = fmaf(e1.x, p1.x, a1); a1 = fmaf(e1.y, p1.y, a1);
                a1 = fmaf(e1.z, p1.z, a1); a1 = fmaf(e1.w, p1.w, a1);
                a2 = fmaf(e2.x, p2.x, a2); a2 = fmaf(e2.y, p2.y, a2);
                a2 = fmaf(e2.z, p2.z, a2); a2 = fmaf(e2.w, p2.w, a2);
                a3 = fmaf(e3.x, p3.x, a3); a3 = fmaf(e3.y, p3.y, a3);
                a3 = fmaf(e3.z, p3.z, a3); a3 = fmaf(e3.w, p3.w, a3);
                b0 = fmaf(e0.x, q0.x, b0); b0 = fmaf(e0.y, q0.y, b0);
                b0 = fmaf(e0.z, q0.z, b0); b0 = fmaf(e0.w, q0.w, b0);
                b1 = fmaf(e1.x, q1.x, b1); b1 = fmaf(e1.y, q1.y, b1);
                b1 = fmaf(e1.z, q1.z, b1); b1 = fmaf(e1.w, q1.w, b1);
                b2 = fmaf(e2.x, q2.x, b2); b2 = fmaf(e2.y, q2.y, b2);
                b2 = fmaf(e2.z, q2.z, b2); b2 = fmaf(e2.w, q2.w, b2);
                b3 = fmaf(e3.x, q3.x, b3); b3 = fmaf(e3.y, q3.y, b3);
                b3 = fmaf(e3.z, q3.z, b3); b3 = fmaf(e3.w, q3.w, b3);
            }
            float sA = (a0 + a1) + (a2 + a3);
            float sB = (b0 + b1) + (b2 + b3);
            if (sA > bestA) { bestA = sA; biA = c; }
            if (sB > bestB) { bestB = sB; biB = c; }
        }
#pragma unroll
        for (int d = 1; d < 64; d <<= 1) {
            float oA = __shfl_xor(bestA, d, 64);
            int   iA = __shfl_xor(biA, d, 64);
            bool  sA = (oA > bestA) || (oA == bestA && iA < biA);
            bestA = sA ? oA : bestA;
            biA   = sA ? iA : biA;
            float oB = __shfl_xor(bestB, d, 64);
            int   iB = __shfl_xor(biB, d, 64);
            bool  sB = (oB > bestB) || (oB == bestB && iB < biB);
            bestB = sB ? oB : bestB;
            biB   = sB ? iB : biB;
        }
        // bestA/biA/bestB/biB are wave-uniform after the full butterfly.
        if (lane == 0) {
            out_ind[r0] = (float)biA;
            row_mse[r0] = ssA - 2.0f * bestA;     // exact ||x||^2 - 2 x.e + ||e||^2
            out_ind[r1] = (float)biB;
            row_mse[r1] = ssB - 2.0f * bestB;
        }
        // Rewrite quantize rows (lanes 0-15 -> r0, 16-31 -> r1).
        {
            int half = lane >> 4;
            int fi   = lane & 15;
            if (half == 0) {
                ((float4*)(out_q + (size_t)r0 * DIM))[fi] =
                    ((const float4*)(embedT + (size_t)biA * DIM))[fi];
            } else if (half == 1) {
                ((float4*)(out_q + (size_t)r1 * DIM))[fi] =
                    ((const float4*)(embedT + (size_t)biB * DIM))[fi];
            }
        }
    }
}

// ---------------------------------------------------------------------------
// Deterministic reduction of row_mse -> 512 block partials (fixed order).
__global__ __launch_bounds__(256) void vq_mse_reduce(const float* __restrict__ row_mse,
                                                     float* __restrict__ partials) {
    __shared__ float wsum[4];
    const int tid = threadIdx.x;
    float acc = row_mse[blockIdx.x * 256 + tid];
#pragma unroll
    for (int off = 32; off > 0; off >>= 1) acc += __shfl_down(acc, off, 64);
    if ((tid & 63) == 0) wsum[tid >> 6] = acc;
    __syncthreads();
    if (tid == 0) partials[blockIdx.x] = (wsum[0] + wsum[1]) + (wsum[2] + wsum[3]);
}

// ---------------------------------------------------------------------------
__global__ __launch_bounds__(256) void vq_finalize(const float* __restrict__ partials,
                                                   float* __restrict__ out,
                                                   int out_size) {
    __shared__ float sm[256];
    int t = threadIdx.x;
    float v = partials[t] + partials[t + 256];
    sm[t] = v;
    __syncthreads();
    for (int s = 128; s > 0; s >>= 1) {
        if (t < s) sm[t] += sm[t + s];
        __syncthreads();
    }
    if (t == 0) out[DIFF_OFF] = sm[0] / 8388608.0f;
    if (t == 1 && out_size > NU_OFF) out[NU_OFF] = -1.0f;
}

// ---------------------------------------------------------------------------
extern "C" void kernel_launch(void* const* d_in, const int* in_sizes, int n_in,
                              void* d_out, int out_size, void* d_ws, size_t ws_size,
                              hipStream_t stream) {
    const float* input = (const float*)d_in[0];   // [32,64,64,64]
    const float* embed = (const float*)d_in[1];   // [64,1024]
    float* out = (float*)d_out;
    float* ws  = (float*)d_ws;

    float* hee      = ws + WS_HEE;
    float* embedT   = ws + WS_EMBEDT;
    float* partials = ws + WS_PARTIALS;
    float* row_mse  = ws + WS_RMSE;
    int*   counter  = (int*)(ws + WS_COUNTER);
    int*   flaglist = (int*)(ws + WS_FLAGLIST);
    unsigned char* bpk = (unsigned char*)(ws + WS_BPK);

    vq_prep<<<36, 256, 0, stream>>>(embed, embedT, hee, counter, bpk);
    vq_score_mfma<<<1024, 256, 0, stream>>>(input, bpk, embedT,
                                            out, out + IND_OFF, row_mse,
                                            counter, flaglist);
    vq_rescore<<<2048, 64, 0, stream>>>(input, embedT, hee, counter, flaglist,
                                        out, out + IND_OFF, row_mse);
    vq_mse_reduce<<<512, 256, 0, stream>>>(row_mse, partials);
    vq_finalize<<<1, 256, 0, stream>>>(partials, out, out_size);
}

// Round 17
// 91.539 us; speedup vs baseline: 3.9453x; 1.0756x over previous
//
#include <hip/hip_runtime.h>
#include <hip/hip_bf16.h>

// Problem constants (fixed by reference)
#define DIM      64
#define NCODE    1024
#define NROWS    131072          // 32*64*64
#define NTILES   64              // 1024 codes / 16 per MFMA tile
#define TAU      0.006f          // near-tie threshold (covers screen+mask error 4x)
#define TSTRIDE  4160            // packed tile: 64B hee + 4x1024B fragments

typedef __attribute__((ext_vector_type(8))) short  short8;  // 8 bf16 (4 VGPRs)
typedef __attribute__((ext_vector_type(4))) float  f32x4;

// Output layout (concatenated in reference return order, all f32):
#define DIFF_OFF 8388608
#define IND_OFF  8388609
#define NU_OFF   (8388609 + 131072)

// ws layout (float offsets)
#define WS_HEE      0            // 1024
#define WS_EMBEDT   1024         // 65536
#define WS_PARTIALS 66560        // 512
#define WS_RMSE     67072        // 131072 (per-row mse)
#define WS_COUNTER  198144       // 1 (int)
#define WS_FLAGLIST 198145       // 131072 (int)
#define WS_BPK      329220       // 66560 floats = 260 KiB packed codebook

__device__ __forceinline__ unsigned short bf16rn(float f) {
    unsigned int u = __float_as_uint(f);
    return (unsigned short)((u + 0x7FFFu + ((u >> 16) & 1u)) >> 16);
}
__device__ __forceinline__ float bf16tof(unsigned short h) {
    return __uint_as_float(((unsigned int)h) << 16);
}
__device__ __forceinline__ unsigned umin_(unsigned a, unsigned b) { return a < b ? a : b; }
__device__ __forceinline__ unsigned umax_(unsigned a, unsigned b) { return a > b ? a : b; }

// ---------------------------------------------------------------------------
// Fused prep (blocks 0..3) + codebook pack (blocks 4..35).  (unchanged)
__global__ __launch_bounds__(256) void vq_prep(const float* __restrict__ embed,
                                               float* __restrict__ embedT,
                                               float* __restrict__ hee,
                                               int* __restrict__ counter,
                                               unsigned char* __restrict__ bpk) {
    if (blockIdx.x < 4) {
        int c = blockIdx.x * 256 + threadIdx.x;      // 0..1023
        if (c == 0) *counter = 0;
        float s = 0.f;
#pragma unroll
        for (int d = 0; d < DIM; ++d) {
            float v = embed[d * NCODE + c];
            embedT[c * DIM + d] = v;
            s = fmaf(v, v, s);
        }
        hee[c] = 0.5f * s;
    } else {
        int t  = (blockIdx.x - 4) * 256 + threadIdx.x;   // 0..8191
        int s  = t & 1;
        int l  = (t >> 1) & 63;
        int ct = t >> 7;
        int c  = ct * 16 + (l & 15);
        int kb = s * 32 + (l >> 4) * 8;

        unsigned int hw[4], lw[4];
#pragma unroll
        for (int w = 0; w < 4; ++w) {
            float v0 = embed[(kb + 2 * w)     * NCODE + c];
            float v1 = embed[(kb + 2 * w + 1) * NCODE + c];
            unsigned short h0 = bf16rn(v0), h1 = bf16rn(v1);
            unsigned short l0 = bf16rn(v0 - bf16tof(h0));
            unsigned short l1 = bf16rn(v1 - bf16tof(h1));
            hw[w] = (unsigned int)h0 | ((unsigned int)h1 << 16);
            lw[w] = (unsigned int)l0 | ((unsigned int)l1 << 16);
        }
        uint4* dst_h = (uint4*)(bpk + ct * TSTRIDE + 64 + s * 1024 + l * 16);
        uint4* dst_l = (uint4*)(bpk + ct * TSTRIDE + 64 + s * 1024 + l * 16 + 2048);
        *dst_h = make_uint4(hw[0], hw[1], hw[2], hw[3]);
        *dst_l = make_uint4(lw[0], lw[1], lw[2], lw[3]);
        if (s == 0 && l < 16) {
            float ss = 0.f;
#pragma unroll
            for (int d = 0; d < DIM; ++d) {
                float v = embed[d * NCODE + c];
                ss = fmaf(v, v, ss);
            }
            *(float*)(bpk + ct * TSTRIDE + l * 4) = 0.5f * ss;
        }
    }
}

// ---------------------------------------------------------------------------
// MFMA scoring v8: r13's measured pipeline + coalesced barrier-free epilogue.
// Key fact: after the 16-lane butterfly, the best code ii is UNIFORM within
// each 16-lane group -> no LDS/broadcast needed. Per slot, all 64 lanes do
// outq[row][lc] = embedT[ii][lc] (4x256B contiguous chunks per instruction),
// 8 loads + 8 stores total, no __syncthreads.
#define ISSUE_T(C0, C1, C2, C3, HH, FA, HA)                                   \
    asm volatile("global_load_dwordx4 %0, %1, off"             : "=v"(C0) : "v"(FA)); \
    asm volatile("global_load_dwordx4 %0, %1, off offset:1024" : "=v"(C1) : "v"(FA)); \
    asm volatile("global_load_dwordx4 %0, %1, off offset:2048" : "=v"(C2) : "v"(FA)); \
    asm volatile("global_load_dwordx4 %0, %1, off offset:3072" : "=v"(C3) : "v"(FA)); \
    asm volatile("global_load_dword %0, %1, off"               : "=v"(HH) : "v"(HA));

#define WAITN(N)                                                              \
    asm volatile("s_waitcnt vmcnt(" #N ")" ::: "memory");                     \
    __builtin_amdgcn_sched_barrier(0);

__global__ __launch_bounds__(256, 4) void vq_score_mfma(const float* __restrict__ input,
                                                        const unsigned char* __restrict__ bpk,
                                                        const float* __restrict__ embedT,
                                                        float* __restrict__ out_q,
                                                        float* __restrict__ out_ind,
                                                        float* __restrict__ row_mse,
                                                        int* __restrict__ counter,
                                                        int* __restrict__ flaglist) {
    const int tid   = threadIdx.x;
    const int wid   = tid >> 6;
    const int lane  = tid & 63;
    const int g     = lane >> 4;          // k-group / D-row group
    const int lc    = lane & 15;          // A-row within set / D-col (code)
    const int rbase = (blockIdx.x * 4 + wid) * 32;

    // Build A fragments (NEGATED x, hi+lo bf16) and per-slot hx = 0.5||x||^2+1.
    short8 ah[2][2], al[2][2];
    float  hx[2][4];
#pragma unroll
    for (int m = 0; m < 2; ++m) {
        float ssum = 0.f;
#pragma unroll
        for (int s = 0; s < 2; ++s) {
            const float* xr = input + (size_t)(rbase + m * 16 + lc) * DIM + s * 32 + g * 8;
            float4 f0 = *(const float4*)(xr);
            float4 f1 = *(const float4*)(xr + 4);
            float xf[8] = {f0.x, f0.y, f0.z, f0.w, f1.x, f1.y, f1.z, f1.w};
            short8 h8, l8;
#pragma unroll
            for (int j = 0; j < 8; ++j) {
                ssum = fmaf(xf[j], xf[j], ssum);
                float nx = -xf[j];
                unsigned short hb = bf16rn(nx);
                h8[j] = (short)hb;
                l8[j] = (short)bf16rn(nx - bf16tof(hb));
            }
            ah[m][s] = h8;
            al[m][s] = l8;
        }
        ssum += __shfl_xor(ssum, 16, 64);
        ssum += __shfl_xor(ssum, 32, 64);
#pragma unroll
        for (int j = 0; j < 4; ++j)
            hx[m][j] = 0.5f * __shfl(ssum, g * 4 + j, 64) + 1.0f;
    }

    unsigned m1[8], m2[8];
#pragma unroll
    for (int t = 0; t < 8; ++t) { m1[t] = 0xFFFFFFFFu; m2[t] = 0xFFFFFFFFu; }

    // Per-tile compute: identical math sequence to r8-r13 (same acc init
    // HH+hx order, same MFMA order, same packed-u32 select) on identical
    // bytes -> bit-identical results/flags. setprio(1) wraps each MFMA chain.
#define COMPT(T, C0, C1, C2, C3, HH)                                          \
    {   short8 s0 = __builtin_bit_cast(short8, C0);                           \
        short8 s1 = __builtin_bit_cast(short8, C1);                           \
        short8 s2 = __builtin_bit_cast(short8, C2);                           \
        short8 s3 = __builtin_bit_cast(short8, C3);                           \
        _Pragma("unroll")                                                     \
        for (int m = 0; m < 2; ++m) {                                         \
            f32x4 acc = {(HH) + hx[m][0], (HH) + hx[m][1],                    \
                         (HH) + hx[m][2], (HH) + hx[m][3]};                   \
            __builtin_amdgcn_s_setprio(1);                                    \
            acc = __builtin_amdgcn_mfma_f32_16x16x32_bf16(ah[m][0], s0, acc, 0, 0, 0); \
            acc = __builtin_amdgcn_mfma_f32_16x16x32_bf16(al[m][0], s0, acc, 0, 0, 0); \
            acc = __builtin_amdgcn_mfma_f32_16x16x32_bf16(ah[m][0], s2, acc, 0, 0, 0); \
            acc = __builtin_amdgcn_mfma_f32_16x16x32_bf16(ah[m][1], s1, acc, 0, 0, 0); \
            acc = __builtin_amdgcn_mfma_f32_16x16x32_bf16(al[m][1], s1, acc, 0, 0, 0); \
            acc = __builtin_amdgcn_mfma_f32_16x16x32_bf16(ah[m][1], s3, acc, 0, 0, 0); \
            __builtin_amdgcn_s_setprio(0);                                    \
            _Pragma("unroll")                                                 \
            for (int j = 0; j < 4; ++j) {                                     \
                unsigned bits = __float_as_uint(acc[j]);                      \
                unsigned pk   = (bits & 0xFFFFFFC0u) | (unsigned)(T);         \
                int s = m * 4 + j;                                            \
                m2[s] = umin_(m2[s], umax_(pk, m1[s]));                       \
                m1[s] = umin_(m1[s], pk);                                     \
            }                                                                 \
        } }

    // Address registers, stepped by 2*TSTRIDE per buffer.
    unsigned long long fA = (unsigned long long)(uintptr_t)(bpk + 64 + lane * 16);
    unsigned long long hA = (unsigned long long)(uintptr_t)(bpk + lc * 4);
    unsigned long long fB = fA + TSTRIDE;
    unsigned long long hB = hA + TSTRIDE;

    uint4 a0, a1, a2, a3;  float ahh;   // ping (even tiles)
    uint4 b0, b1, b2, b3;  float bhh;   // pong (odd tiles)

    ISSUE_T(a0, a1, a2, a3, ahh, fA, hA);            // tile 0 in flight
    fA += 2 * TSTRIDE;  hA += 2 * TSTRIDE;

    for (int ct = 0; ct < NTILES - 2; ct += 2) {
        ISSUE_T(b0, b1, b2, b3, bhh, fB, hB);        // tile ct+1 in flight
        fB += 2 * TSTRIDE;  hB += 2 * TSTRIDE;
        WAITN(5);                                    // tile ct ready; ct+1 in flight
        COMPT(ct, a0, a1, a2, a3, ahh);
        ISSUE_T(a0, a1, a2, a3, ahh, fA, hA);        // tile ct+2 in flight
        fA += 2 * TSTRIDE;  hA += 2 * TSTRIDE;
        WAITN(5);                                    // tile ct+1 ready
        COMPT(ct + 1, b0, b1, b2, b3, bhh);
    }
    // Tail: tiles 62 (in flight in A) and 63.
    ISSUE_T(b0, b1, b2, b3, bhh, fB, hB);
    WAITN(5);
    COMPT(NTILES - 2, a0, a1, a2, a3, ahh);
    WAITN(0);
    COMPT(NTILES - 1, b0, b1, b2, b3, bhh);

#undef COMPT

    // Merge + fused coalesced epilogue. After the full d=1..8 butterfly the
    // (v1, ii) pair is uniform across each 16-lane group -> every lane knows
    // its group's winning code; row varies only with g.
#pragma unroll
    for (int m = 0; m < 2; ++m) {
#pragma unroll
        for (int j = 0; j < 4; ++j) {
            int s = m * 4 + j;
            unsigned v1 = m1[s], v2 = m2[s];
            int ii = (int)(((v1 & 63u) << 4) | (unsigned)lc);   // full code
#pragma unroll
            for (int d = 1; d < 16; d <<= 1) {
                unsigned o1 = __shfl_xor(v1, d, 64);
                int      oi = __shfl_xor(ii, d, 64);
                unsigned o2 = __shfl_xor(v2, d, 64);
                bool sw = (o1 < v1) || (o1 == v1 && oi < ii);
                unsigned losing = sw ? v1 : o1;
                v2 = umin_(umin_(v2, o2), losing);
                v1 = sw ? o1 : v1;
                ii = sw ? oi : ii;
            }
            int row = rbase + m * 16 + g * 4 + j;    // per-lane (g varies)
            // Coalesced quantize write: 16 lanes cover one 256B row chunk.
            ((float4*)(out_q + (size_t)row * DIM))[lc] =
                ((const float4*)(embedT + (size_t)ii * DIM))[lc];
            if (lc == 0) {
                out_ind[row] = (float)ii;
                // mse estimate from the masked distance: mse = 2*(d-1).
                row_mse[row] = 2.0f * (__uint_as_float(v1 & 0xFFFFFFC0u) - 1.0f);
                float gap = __uint_as_float(v2 & 0xFFFFFFC0u)
                          - __uint_as_float(v1 & 0xFFFFFFC0u);
                if (gap < TAU) {
                    int p = atomicAdd(counter, 1);
                    flaglist[p] = row;
                }
            }
        }
    }
}

// ---------------------------------------------------------------------------
// Exact rescore, 2 flagged rows per embedT sweep; rewrites quantize rows,
// ind, and exact row_mse (= ||x||^2 - 2*s_best) in place.  (unchanged r13)
__global__ __launch_bounds__(64) void vq_rescore(const float* __restrict__ input,
                                                 const float* __restrict__ embedT,
                                                 const float* __restrict__ hee,
                                                 const int* __restrict__ counter,
                                                 const int* __restrict__ flaglist,
                                                 float* __restrict__ out_q,
                                                 float* __restrict__ out_ind,
                                                 float* __restrict__ row_mse) {
    const int lane = threadIdx.x;
    const int cnt  = *counter;
    for (int i = blockIdx.x * 2; i < cnt; i += gridDim.x * 2) {
        const int r0 = flaglist[i];
        const int r1 = (i + 1 < cnt) ? flaglist[i + 1] : r0;
        float4 xa[16], xb[16];
        float ssA = 0.f, ssB = 0.f;
        {
            const float4* pa = (const float4*)(input + (size_t)r0 * DIM);
            const float4* pb = (const float4*)(input + (size_t)r1 * DIM);
#pragma unroll
            for (int k = 0; k < 16; ++k) {
                xa[k] = pa[k]; xb[k] = pb[k];
                ssA = fmaf(xa[k].x, xa[k].x, ssA); ssA = fmaf(xa[k].y, xa[k].y, ssA);
                ssA = fmaf(xa[k].z, xa[k].z, ssA); ssA = fmaf(xa[k].w, xa[k].w, ssA);
                ssB = fmaf(xb[k].x, xb[k].x, ssB); ssB = fmaf(xb[k].y, xb[k].y, ssB);
                ssB = fmaf(xb[k].z, xb[k].z, ssB); ssB = fmaf(xb[k].w, xb[k].w, ssB);
            }
        }
        float bestA = -3.402823466e+38f, bestB = -3.402823466e+38f;
        int   biA = 0, biB = 0;
#pragma unroll 1
        for (int k = 0; k < 16; ++k) {
            int c = lane * 16 + k;
            const float4* e4 = (const float4*)(embedT + (size_t)c * DIM);
            float hh = hee[c];
            float a0 = -hh, a1 = 0.f, a2 = 0.f, a3 = 0.f;
            float b0 = -hh, b1 = 0.f, b2 = 0.f, b3 = 0.f;
#pragma unroll
            for (int q = 0; q < 4; ++q) {
                float4 e0 = e4[4 * q + 0], e1 = e4[4 * q + 1];
                float4 e2 = e4[4 * q + 2], e3 = e4[4 * q + 3];
                float4 p0 = xa[4 * q + 0], p1 = xa[4 * q + 1];
                float4 p2 = xa[4 * q + 2], p3 = xa[4 * q + 3];
                float4 q0 = xb[4 * q + 0], q1 = xb[4 * q + 1];
                float4 q2 = xb[4 * q + 2], q3 = xb[4 * q + 3];
                a0 = fmaf(e0.x, p0.x, a0); a0 = fmaf(e0.y, p0.y, a0);
                a0 = fmaf(e0.z, p0.z, a0); a0 = fmaf(e0.w, p0.w, a0);
                a1 = fmaf(e1.x, p1.x, a1); a1 = fmaf(e1.y, p1.y, a1);
                a1 = fmaf(e1.z, p1.z, a1); a1 = fmaf(e1.w, p1.w, a1);
                a2 = fmaf(e2.x, p2.x, a2); a2 = fmaf(e2.y, p2.y, a2);
                a2 = fmaf(e2.z, p2.z, a2); a2 = fmaf(e2.w, p2.w, a2);
                a3 = fmaf(e3.x, p3.x, a3); a3 = fmaf(e3.y, p3.y, a3);
                a3 = fmaf(e3.z, p3.z, a3); a3 = fmaf(e3.w, p3.w, a3);
                b0 = fmaf(e0.x, q0.x, b0); b0 = fmaf(e0.y, q0.y, b0);
                b0 = fmaf(e0.z, q0.z, b0); b0 = fmaf(e0.w, q0.w, b0);
                b1 = fmaf(e1.x, q1.x, b1); b1 = fmaf(e1.y, q1.y, b1);
                b1 = fmaf(e1.z, q1.z, b1); b1 = fmaf(e1.w, q1.w, b1);
                b2 = fmaf(e2.x, q2.x, b2); b2 = fmaf(e2.y, q2.y, b2);
                b2 = fmaf(e2.z, q2.z, b2); b2 = fmaf(e2.w, q2.w, b2);
                b3 = fmaf(e3.x, q3.x, b3); b3 = fmaf(e3.y, q3.y, b3);
                b3 = fmaf(e3.z, q3.z, b3); b3 = fmaf(e3.w, q3.w, b3);
            }
            float sA = (a0 + a1) + (a2 + a3);
            float sB = (b0 + b1) + (b2 + b3);
            if (sA > bestA) { bestA = sA; biA = c; }
            if (sB > bestB) { bestB = sB; biB = c; }
        }
#pragma unroll
        for (int d = 1; d < 64; d <<= 1) {
            float oA = __shfl_xor(bestA, d, 64);
            int   iA = __shfl_xor(biA, d, 64);
            bool  sA = (oA > bestA) || (oA == bestA && iA < biA);
            bestA = sA ? oA : bestA;
            biA   = sA ? iA : biA;
            float oB = __shfl_xor(bestB, d, 64);
            int   iB = __shfl_xor(biB, d, 64);
            bool  sB = (oB > bestB) || (oB == bestB && iB < biB);
            bestB = sB ? oB : bestB;
            biB   = sB ? iB : biB;
        }
        if (lane == 0) {
            out_ind[r0] = (float)biA;
            row_mse[r0] = ssA - 2.0f * bestA;
            out_ind[r1] = (float)biB;
            row_mse[r1] = ssB - 2.0f * bestB;
        }
        {
            int half = lane >> 4;
            int fi   = lane & 15;
            if (half == 0) {
                ((float4*)(out_q + (size_t)r0 * DIM))[fi] =
                    ((const float4*)(embedT + (size_t)biA * DIM))[fi];
            } else if (half == 1) {
                ((float4*)(out_q + (size_t)r1 * DIM))[fi] =
                    ((const float4*)(embedT + (size_t)biB * DIM))[fi];
            }
        }
    }
}

// ---------------------------------------------------------------------------
// Deterministic reduction of row_mse -> 512 block partials (fixed order).
__global__ __launch_bounds__(256) void vq_mse_reduce(const float* __restrict__ row_mse,
                                                     float* __restrict__ partials) {
    __shared__ float wsum[4];
    const int tid = threadIdx.x;
    float acc = row_mse[blockIdx.x * 256 + tid];
#pragma unroll
    for (int off = 32; off > 0; off >>= 1) acc += __shfl_down(acc, off, 64);
    if ((tid & 63) == 0) wsum[tid >> 6] = acc;
    __syncthreads();
    if (tid == 0) partials[blockIdx.x] = (wsum[0] + wsum[1]) + (wsum[2] + wsum[3]);
}

// ---------------------------------------------------------------------------
__global__ __launch_bounds__(256) void vq_finalize(const float* __restrict__ partials,
                                                   float* __restrict__ out,
                                                   int out_size) {
    __shared__ float sm[256];
    int t = threadIdx.x;
    float v = partials[t] + partials[t + 256];
    sm[t] = v;
    __syncthreads();
    for (int s = 128; s > 0; s >>= 1) {
        if (t < s) sm[t] += sm[t + s];
        __syncthreads();
    }
    if (t == 0) out[DIFF_OFF] = sm[0] / 8388608.0f;
    if (t == 1 && out_size > NU_OFF) out[NU_OFF] = -1.0f;
}

// ---------------------------------------------------------------------------
extern "C" void kernel_launch(void* const* d_in, const int* in_sizes, int n_in,
                              void* d_out, int out_size, void* d_ws, size_t ws_size,
                              hipStream_t stream) {
    const float* input = (const float*)d_in[0];   // [32,64,64,64]
    const float* embed = (const float*)d_in[1];   // [64,1024]
    float* out = (float*)d_out;
    float* ws  = (float*)d_ws;

    float* hee      = ws + WS_HEE;
    float* embedT   = ws + WS_EMBEDT;
    float* partials = ws + WS_PARTIALS;
    float* row_mse  = ws + WS_RMSE;
    int*   counter  = (int*)(ws + WS_COUNTER);
    int*   flaglist = (int*)(ws + WS_FLAGLIST);
    unsigned char* bpk = (unsigned char*)(ws + WS_BPK);

    vq_prep<<<36, 256, 0, stream>>>(embed, embedT, hee, counter, bpk);
    vq_score_mfma<<<1024, 256, 0, stream>>>(input, bpk, embedT,
                                            out, out + IND_OFF, row_mse,
                                            counter, flaglist);
    vq_rescore<<<2048, 64, 0, stream>>>(input, embedT, hee, counter, flaglist,
                                        out, out + IND_OFF, row_mse);
    vq_mse_reduce<<<512, 256, 0, stream>>>(row_mse, partials);
    vq_finalize<<<1, 256, 0, stream>>>(partials, out, out_size);
}